// Round 1
// baseline (5998.028 us; speedup 1.0000x reference)
//
#include <hip/hip_runtime.h>
#include <hip/hip_bf16.h>

#define B_ 128
#define T_ 256
#define E_ 128
#define H_ 256
#define K_ 32
#define G4H 1024   // 4*H
#define KTOT 384   // E + H

__device__ __forceinline__ float sigf(float z) { return 1.0f / (1.0f + expf(-z)); }

// ---------------- mask dtype detect + lengths ----------------
// mask may arrive as bool8, int32, or int64. Detect from first 32KB (safe
// under every layout: int32 buffer is 128KB, int64 256KB, bool8 32KB).
__global__ void k_lengths(const unsigned* __restrict__ maskw, int* __restrict__ lengths) {
  __shared__ int flagBad;   // any word with value > 1  -> byte-packed bool
  __shared__ int flagOdd;   // any odd-indexed word nonzero -> not int64
  int tid = threadIdx.x;
  if (tid == 0) { flagBad = 0; flagOdd = 0; }
  __syncthreads();
  int bad = 0, odd = 0;
  for (int i = tid; i < (B_ * T_) / 4; i += 256) {   // 8192 words = 32KB
    unsigned v = maskw[i];
    if (v > 1u) bad = 1;
    if ((i & 1) && v) odd = 1;
  }
  if (bad) atomicOr(&flagBad, 1);
  if (odd) atomicOr(&flagOdd, 1);
  __syncthreads();
  int mode = flagBad ? 0 : (flagOdd ? 1 : 2);  // 0=bool8, 1=int32, 2=int64
  for (int b = tid; b < B_; b += 256) {
    int cnt = 0;
    if (mode == 0) {
      const unsigned char* mb = (const unsigned char*)maskw;
      for (int t = 0; t < T_; ++t) cnt += (mb[b * T_ + t] != 0);
    } else if (mode == 1) {
      for (int t = 0; t < T_; ++t) cnt += (maskw[b * T_ + t] != 0);
    } else {
      for (int t = 0; t < T_; ++t) cnt += (maskw[(size_t)(b * T_ + t) * 2] != 0);
    }
    if (cnt < 1) cnt = 1;
    lengths[b] = cnt;
  }
}

// ---------------- pack weights: wc[d][k][j][p] ----------------
// k in [0,384): 0..127 = wih rows (transposed), 128..383 = whh rows.
// jj = j*2+p stores gate g = p*512 + j so a float2 load gives gates (j, 512+j).
__global__ void k_packw(const float* __restrict__ wih_f, const float* __restrict__ whh_f,
                        const float* __restrict__ wih_b, const float* __restrict__ whh_b,
                        float* __restrict__ wc) {
  int e = blockIdx.x * 256 + threadIdx.x;
  if (e >= 2 * KTOT * G4H) return;
  int d = e / (KTOT * G4H);
  int r = e - d * (KTOT * G4H);
  int k = r >> 10;
  int jj = r & 1023;
  int j = jj >> 1, p = jj & 1;
  int g = p * 512 + j;
  const float* wih = d ? wih_b : wih_f;
  const float* whh = d ? whh_b : whh_f;
  float v = (k < E_) ? wih[g * E_ + k] : whh[g * H_ + (k - E_)];
  wc[e] = v;
}

__global__ void k_bias(const float* __restrict__ bih_f, const float* __restrict__ bhh_f,
                       const float* __restrict__ bih_b, const float* __restrict__ bhh_b,
                       float* __restrict__ bias) {
  int e = blockIdx.x * 256 + threadIdx.x;
  if (e >= 2 * G4H) return;
  int d = e >> 10, j = e & 1023;
  bias[e] = d ? (bih_b[j] + bhh_b[j]) : (bih_f[j] + bhh_f[j]);
}

// ---------------- embedding gather ----------------
__global__ void k_gather(const int* __restrict__ tokens, const float* __restrict__ embed,
                         float* __restrict__ x) {
  int idx = blockIdx.x * 256 + threadIdx.x;   // float4 index
  int p = idx >> 5, e4 = idx & 31;            // 32 float4 per row of E=128
  int tok = tokens[p];
  ((float4*)x)[(size_t)p * 32 + e4] = ((const float4*)embed)[(size_t)tok * 32 + e4];
}

// ---------------- fused LSTM (input proj + recurrence) ----------------
// One WG per (direction, 4 batch rows). 512 threads.
// Thread tid accumulates gates (tid, 512+tid) for all 4 rows. K-loop over
// concat(x_t, h) of length 384 held in LDS as float4 (one lane per row).
__global__ __launch_bounds__(512) void k_lstm(const float* __restrict__ x,
    const float* __restrict__ wc, const float* __restrict__ bias,
    float* __restrict__ hf, float* __restrict__ hb) {
  const int dir = blockIdx.y;
  const int b0 = blockIdx.x * 4;
  const float2* __restrict__ w2 = (const float2*)(wc + (size_t)dir * KTOT * G4H);
  const float* bias_d = bias + dir * G4H;
  float* __restrict__ hout = dir ? hb : hf;
  __shared__ float4 vs[KTOT];        // [k] -> component r = batch row b0+r
  __shared__ float gbuf[4][G4H];     // gates per row
  const int tid = threadIdx.x;
  float c0 = 0.f, c1 = 0.f;
  const float bj0 = bias_d[tid], bj1 = bias_d[512 + tid];
  if (tid < H_) vs[E_ + tid] = make_float4(0.f, 0.f, 0.f, 0.f);  // h = 0
  const int rr = tid >> 7, hu = (tid & 127) * 2;
  const int kx = tid & 127, rx = tid >> 7;
  __syncthreads();
  for (int s = 0; s < T_; ++s) {
    const int t = dir ? (T_ - 1 - s) : s;
    // stage x_t for 4 rows
    ((float*)&vs[kx])[rx] = x[((size_t)(b0 + rx) * T_ + t) * E_ + kx];
    __syncthreads();
    float a00 = bj0, a01 = bj0, a02 = bj0, a03 = bj0;
    float a10 = bj1, a11 = bj1, a12 = bj1, a13 = bj1;
#pragma unroll 4
    for (int k = 0; k < KTOT; ++k) {
      float2 w = w2[(size_t)k * 512 + tid];
      float4 v = vs[k];
      a00 += w.x * v.x; a01 += w.x * v.y; a02 += w.x * v.z; a03 += w.x * v.w;
      a10 += w.y * v.x; a11 += w.y * v.y; a12 += w.y * v.z; a13 += w.y * v.w;
    }
    __syncthreads();   // all vs reads done before h-part overwrite
    gbuf[0][tid] = a00; gbuf[1][tid] = a01; gbuf[2][tid] = a02; gbuf[3][tid] = a03;
    gbuf[0][512 + tid] = a10; gbuf[1][512 + tid] = a11; gbuf[2][512 + tid] = a12; gbuf[3][512 + tid] = a13;
    __syncthreads();
    // cell update: thread -> (row rr, hidden units hu, hu+1)
    {
      float ig = gbuf[rr][hu], fg = gbuf[rr][H_ + hu], gg = gbuf[rr][2 * H_ + hu], og = gbuf[rr][3 * H_ + hu];
      c0 = sigf(fg) * c0 + sigf(ig) * tanhf(gg);
      float hn = sigf(og) * tanhf(c0);
      ((float*)&vs[E_ + hu])[rr] = hn;
      hout[((size_t)(b0 + rr) * T_ + t) * H_ + hu] = hn;
      int h2 = hu + 1;
      float ig2 = gbuf[rr][h2], fg2 = gbuf[rr][H_ + h2], gg2 = gbuf[rr][2 * H_ + h2], og2 = gbuf[rr][3 * H_ + h2];
      c1 = sigf(fg2) * c1 + sigf(ig2) * tanhf(gg2);
      float hn2 = sigf(og2) * tanhf(c1);
      ((float*)&vs[E_ + h2])[rr] = hn2;
      hout[((size_t)(b0 + rr) * T_ + t) * H_ + h2] = hn2;
    }
    // no barrier needed here: next x-stage writes vs[0..127] (disjoint) and the
    // following barrier orders everything before the next K-loop.
  }
}

// ---------------- emissions: em = concat(hf,hb) @ w_lin^T + b_lin ----------------
__global__ __launch_bounds__(256) void k_emis(const float* __restrict__ hf, const float* __restrict__ hb,
    const float* __restrict__ w_lin, const float* __restrict__ b_lin, float* __restrict__ em) {
  __shared__ float hsl[8][512];
  __shared__ float red[8][8][K_];
  const int tid = threadIdx.x;
  const int pos0 = blockIdx.x * 8;   // linear position p = b*T + t
  for (int it = 0; it < 4; ++it) {
    int idx = it * 256 + tid;        // float4 index in [8][128]
    int rr = idx >> 7, c4 = idx & 127;
    const float* src = (c4 < 64) ? (hf + ((size_t)(pos0 + rr)) * H_ + (c4 * 4))
                                 : (hb + ((size_t)(pos0 + rr)) * H_ + ((c4 - 64) * 4));
    float4 v = *(const float4*)src;
    *(float4*)&hsl[rr][c4 * 4] = v;
  }
  __syncthreads();
  const int k = tid & 31, jc = tid >> 5;
  float wreg[64];
#pragma unroll
  for (int i4 = 0; i4 < 16; ++i4) {
    float4 w = *(const float4*)(w_lin + (size_t)k * 512 + jc * 64 + i4 * 4);
    wreg[i4 * 4 + 0] = w.x; wreg[i4 * 4 + 1] = w.y; wreg[i4 * 4 + 2] = w.z; wreg[i4 * 4 + 3] = w.w;
  }
  float acc[8];
  for (int rr = 0; rr < 8; ++rr) {
    float a = 0.f;
#pragma unroll
    for (int i4 = 0; i4 < 16; ++i4) {
      float4 h = *(const float4*)&hsl[rr][jc * 64 + i4 * 4];
      a += wreg[i4 * 4 + 0] * h.x + wreg[i4 * 4 + 1] * h.y + wreg[i4 * 4 + 2] * h.z + wreg[i4 * 4 + 3] * h.w;
    }
    acc[rr] = a;
  }
  for (int rr2 = 0; rr2 < 8; ++rr2) red[rr2][jc][k] = acc[rr2];
  __syncthreads();
  {
    int rr = tid >> 5, kk = tid & 31;
    float s = b_lin[kk];
#pragma unroll
    for (int j = 0; j < 8; ++j) s += red[rr][j][kk];
    em[((size_t)(pos0 + rr)) * K_ + kk] = s;
  }
}

// ---------------- Viterbi (one WG = one batch row, history in LDS) ----------------
__global__ __launch_bounds__(64) void k_viterbi(const float* __restrict__ em,
    const int* __restrict__ lengths, const float* __restrict__ start_t,
    const float* __restrict__ end_t, const float* __restrict__ trans,
    int* __restrict__ out) {
  const int b = blockIdx.x;
  const int lane = threadIdx.x;
  __shared__ unsigned char hist[T_ - 1][K_];
  __shared__ float sl[K_];
  const int len = lengths[b];
  float tc[K_];
  float score = 0.f;
  if (lane < K_) {
#pragma unroll
    for (int i = 0; i < K_; ++i) tc[i] = trans[i * K_ + lane];   // trans[:, lane]
    score = start_t[lane] + em[((size_t)b * T_) * K_ + lane];
  }
  for (int t = 1; t < T_; ++t) {
    float emk = 0.f;
    if (lane < K_) {
      emk = em[((size_t)b * T_ + t) * K_ + lane];
      sl[lane] = score;
    }
    __syncthreads();
    if (lane < K_) {
      float best = sl[0] + tc[0]; int bi = 0;
#pragma unroll
      for (int i = 1; i < K_; ++i) {
        float c = sl[i] + tc[i];
        if (c > best) { best = c; bi = i; }   // strict > = first-occurrence argmax
      }
      hist[t - 1][lane] = (unsigned char)bi;
      if (t < len) score = best + emk;        // masked steps keep old score
    }
    __syncthreads();
  }
  if (lane < K_) sl[lane] = score + end_t[lane];
  __syncthreads();
  int* outb = out + (size_t)b * T_;
  for (int t = lane; t < T_; t += 64)
    if (t >= len) outb[t] = 0;
  if (lane == 0) {
    float best = sl[0]; int cur = 0;
    for (int k2 = 1; k2 < K_; ++k2)
      if (sl[k2] > best) { best = sl[k2]; cur = k2; }
    outb[len - 1] = cur;
    for (int t = len - 2; t >= 0; --t) { cur = hist[t][cur]; outb[t] = cur; }
  }
}

extern "C" void kernel_launch(void* const* d_in, const int* in_sizes, int n_in,
                              void* d_out, int out_size, void* d_ws, size_t ws_size,
                              hipStream_t stream) {
  const int* tokens   = (const int*)d_in[0];
  const unsigned* maskw = (const unsigned*)d_in[1];
  const float* embed  = (const float*)d_in[2];
  const float* wih_f  = (const float*)d_in[3];
  const float* whh_f  = (const float*)d_in[4];
  const float* bih_f  = (const float*)d_in[5];
  const float* bhh_f  = (const float*)d_in[6];
  const float* wih_b  = (const float*)d_in[7];
  const float* whh_b  = (const float*)d_in[8];
  const float* bih_b  = (const float*)d_in[9];
  const float* bhh_b  = (const float*)d_in[10];
  const float* w_lin  = (const float*)d_in[11];
  const float* b_lin  = (const float*)d_in[12];
  const float* start_t = (const float*)d_in[13];
  const float* end_t  = (const float*)d_in[14];
  const float* trans  = (const float*)d_in[15];
  int* out = (int*)d_out;
  (void)in_sizes; (void)n_in; (void)out_size; (void)ws_size;

  char* ws = (char*)d_ws;
  size_t off = 0;
  auto alloc = [&](size_t bytes) { size_t o = off; off = (off + bytes + 255) & ~(size_t)255; return o; };
  int*   lengths = (int*)(ws + alloc((size_t)B_ * 4));
  float* wc      = (float*)(ws + alloc((size_t)2 * KTOT * G4H * 4));
  float* bias    = (float*)(ws + alloc((size_t)2 * G4H * 4));
  float* x       = (float*)(ws + alloc((size_t)B_ * T_ * E_ * 4));
  float* hf      = (float*)(ws + alloc((size_t)B_ * T_ * H_ * 4));
  float* hb      = (float*)(ws + alloc((size_t)B_ * T_ * H_ * 4));
  float* em      = (float*)(ws + alloc((size_t)B_ * T_ * K_ * 4));

  k_lengths<<<dim3(1), dim3(256), 0, stream>>>(maskw, lengths);
  k_packw<<<dim3((2 * KTOT * G4H + 255) / 256), dim3(256), 0, stream>>>(wih_f, whh_f, wih_b, whh_b, wc);
  k_bias<<<dim3(8), dim3(256), 0, stream>>>(bih_f, bhh_f, bih_b, bhh_b, bias);
  k_gather<<<dim3((B_ * T_ * E_ / 4) / 256), dim3(256), 0, stream>>>(tokens, embed, x);
  k_lstm<<<dim3(B_ / 4, 2), dim3(512), 0, stream>>>(x, wc, bias, hf, hb);
  k_emis<<<dim3(B_ * T_ / 8), dim3(256), 0, stream>>>(hf, hb, w_lin, b_lin, em);
  k_viterbi<<<dim3(B_), dim3(64), 0, stream>>>(em, lengths, start_t, end_t, trans, out);
}

// Round 5
// 3494.438 us; speedup vs baseline: 1.7164x; 1.7164x over previous
//
#include <hip/hip_runtime.h>
#include <hip/hip_bf16.h>

#define B_ 128
#define T_ 256
#define E_ 128
#define H_ 256
#define K_ 32
#define G4H 1024   // 4*H

__device__ __forceinline__ float sigf(float z) { return 1.0f / (1.0f + expf(-z)); }

// ---------------- mask dtype detect + lengths ----------------
__global__ void k_lengths(const unsigned* __restrict__ maskw, int* __restrict__ lengths) {
  __shared__ int flagBad;   // any word with value > 1  -> byte-packed bool
  __shared__ int flagOdd;   // any odd-indexed word nonzero -> not int64
  int tid = threadIdx.x;
  if (tid == 0) { flagBad = 0; flagOdd = 0; }
  __syncthreads();
  int bad = 0, odd = 0;
  for (int i = tid; i < (B_ * T_) / 4; i += 256) {
    unsigned v = maskw[i];
    if (v > 1u) bad = 1;
    if ((i & 1) && v) odd = 1;
  }
  if (bad) atomicOr(&flagBad, 1);
  if (odd) atomicOr(&flagOdd, 1);
  __syncthreads();
  int mode = flagBad ? 0 : (flagOdd ? 1 : 2);  // 0=bool8, 1=int32, 2=int64
  for (int b = tid; b < B_; b += 256) {
    int cnt = 0;
    if (mode == 0) {
      const unsigned char* mb = (const unsigned char*)maskw;
      for (int t = 0; t < T_; ++t) cnt += (mb[b * T_ + t] != 0);
    } else if (mode == 1) {
      for (int t = 0; t < T_; ++t) cnt += (maskw[b * T_ + t] != 0);
    } else {
      for (int t = 0; t < T_; ++t) cnt += (maskw[(size_t)(b * T_ + t) * 2] != 0);
    }
    if (cnt < 1) cnt = 1;
    lengths[b] = cnt;
  }
}

// ---------------- pack weights: wpk[d][o][k4][g][4] ----------------
// g in [0,128): ty = g>>5 (i,f,g,o), unit-in-octant = g&31.
// Original gate row brow = ty*256 + o*32 + (g&31).  k = 4*k4 + p over concat(x,h).
__global__ void k_packw2(const float* __restrict__ wih_f, const float* __restrict__ whh_f,
                         const float* __restrict__ wih_b, const float* __restrict__ whh_b,
                         float* __restrict__ wpk) {
  int e = blockIdx.x * 256 + threadIdx.x;
  if (e >= 2 * 8 * 96 * 128 * 4) return;
  int p = e & 3;
  int g = (e >> 2) & 127;
  int rest = e >> 9;
  int k4 = rest % 96;
  int do_ = rest / 96;
  int o = do_ & 7, d = do_ >> 3;
  int ty = g >> 5;
  int brow = ty * 256 + o * 32 + (g & 31);
  int k = k4 * 4 + p;
  const float* wih = d ? wih_b : wih_f;
  const float* whh = d ? whh_b : whh_f;
  float v = (k < E_) ? wih[brow * E_ + k] : whh[brow * H_ + (k - E_)];
  wpk[e] = v;
}

__global__ void k_bias(const float* __restrict__ bih_f, const float* __restrict__ bhh_f,
                       const float* __restrict__ bih_b, const float* __restrict__ bhh_b,
                       float* __restrict__ bias) {
  int e = blockIdx.x * 256 + threadIdx.x;
  if (e >= 2 * G4H) return;
  int d = e >> 10, j = e & 1023;
  bias[e] = d ? (bih_b[j] + bhh_b[j]) : (bih_f[j] + bhh_f[j]);
}

// ---------------- embedding gather ----------------
__global__ void k_gather(const int* __restrict__ tokens, const float* __restrict__ embed,
                         float* __restrict__ x) {
  int idx = blockIdx.x * 256 + threadIdx.x;   // float4 index
  int p = idx >> 5, e4 = idx & 31;
  int tok = tokens[p];
  ((float4*)x)[(size_t)p * 32 + e4] = ((const float4*)embed)[(size_t)tok * 32 + e4];
}

// ---------------- zero the sync flags (ws is poisoned each call) ----------------
__global__ void k_zero(int* __restrict__ flags) {
  int i = blockIdx.x * 256 + threadIdx.x;
  if (i < 256 * 64) flags[i] = 0;
}

// ---------------- fused LSTM, full-chip ----------------
// 256 WGs = 2 dirs x 16 rowgroups(8 rows) x 8 octants(32 hidden units).
// Each WG computes 128 gate rows (4 types x 32 units) for its 8 batch rows.
// Cross-WG h exchange per step via device-scope relaxed atomics (L3) with
// per-WG release flags; h double-buffered by step parity.
__global__ __launch_bounds__(512) void k_lstm2(const float* __restrict__ x,
    const float* __restrict__ wpk, const float* __restrict__ bias,
    float* __restrict__ hf, float* __restrict__ hb,
    float* __restrict__ hx, int* __restrict__ flags) {
  const int wg = blockIdx.x;          // 0..255
  const int o  = wg & 7;              // octant
  const int rb = (wg >> 3) & 15;      // row block
  const int d  = wg >> 7;             // dir
  const int b0 = rb * 8;
  const int tid = threadIdx.x;
  __shared__ float vs[384 * 10];      // [k][10] (8 rows used, pad to 10)
  __shared__ float gbuf[128 * 10];    // [g][10]
  const float4* __restrict__ w4 = (const float4*)(wpk + (size_t)(d * 8 + o) * 96 * 128 * 4);
  const int g = tid & 127, rp = tid >> 7;           // gate, row-pair
  const int ty = g >> 5;
  const int brow = ty * 256 + o * 32 + (g & 31);
  const float bj = bias[d * G4H + brow];
  float* __restrict__ hout = d ? hb : hf;
  float* __restrict__ hxg = hx + (size_t)(d * 16 + rb) * 2 * 2048;  // [par][256u][8r]
  int* __restrict__ flagg = flags + (d * 16 + rb) * 8 * 64;         // 8 flags, stride 64
  const int uu = (tid & 255) >> 3, rr = tid & 7;    // cell-update role (tid<256)
  float creg = 0.f;
  for (int s = 0; s < T_; ++s) {
    const int t = d ? (T_ - 1 - s) : s;
    if (s > 0 && tid < 8) {
      int* fp = flagg + tid * 64;
      while (__hip_atomic_load(fp, __ATOMIC_RELAXED, __HIP_MEMORY_SCOPE_AGENT) < s) {}
    }
    __syncthreads();
    // stage x_t: 1024 floats, coalesced rows
    {
      int idx = tid;
#pragma unroll
      for (int j = 0; j < 2; ++j, idx += 512) {
        int r = idx >> 7, e = idx & 127;
        vs[e * 10 + r] = x[((size_t)(b0 + r) * T_ + t) * E_ + e];
      }
    }
    // stage h_s (zeros at s=0; else from L3 exchange buffer, parity s&1)
    if (s == 0) {
      int idx = tid;
#pragma unroll
      for (int j = 0; j < 4; ++j, idx += 512) {
        int u = idx >> 3, r = idx & 7;
        vs[(E_ + u) * 10 + r] = 0.f;
      }
    } else {
      const float* hsrc = hxg + (size_t)(s & 1) * 2048;
      int idx = tid;
#pragma unroll
      for (int j = 0; j < 4; ++j, idx += 512) {
        int u = idx >> 3, r = idx & 7;
        float hv = __hip_atomic_load((float*)(hsrc + idx), __ATOMIC_RELAXED, __HIP_MEMORY_SCOPE_AGENT);
        vs[(E_ + u) * 10 + r] = hv;
      }
    }
    __syncthreads();
    // gate GEMM: thread = (gate g, rows rp*2, rp*2+1)
    float a0 = bj, a1 = bj;
    const float* vsp = vs + rp * 2;
#pragma unroll 8
    for (int k4 = 0; k4 < 96; ++k4) {
      float4 w = w4[(size_t)k4 * 128 + g];
      float2 v0 = *(const float2*)(vsp + (4 * k4 + 0) * 10);
      float2 v1 = *(const float2*)(vsp + (4 * k4 + 1) * 10);
      float2 v2 = *(const float2*)(vsp + (4 * k4 + 2) * 10);
      float2 v3 = *(const float2*)(vsp + (4 * k4 + 3) * 10);
      a0 += w.x * v0.x + w.y * v1.x + w.z * v2.x + w.w * v3.x;
      a1 += w.x * v0.y + w.y * v1.y + w.z * v2.y + w.w * v3.y;
    }
    *(float2*)&gbuf[g * 10 + rp * 2] = make_float2(a0, a1);
    __syncthreads();
    // cell update: thread (unit uu, row rr), tid<256
    if (tid < 256) {
      float ig = gbuf[(uu) * 10 + rr];
      float fg = gbuf[(32 + uu) * 10 + rr];
      float gg = gbuf[(64 + uu) * 10 + rr];
      float og = gbuf[(96 + uu) * 10 + rr];
      creg = sigf(fg) * creg + sigf(ig) * tanhf(gg);
      float hn = sigf(og) * tanhf(creg);
      int ugl = o * 32 + uu;
      hout[((size_t)(b0 + rr) * T_ + t) * H_ + ugl] = hn;
      __hip_atomic_store(hxg + (size_t)((s + 1) & 1) * 2048 + ugl * 8 + rr, hn,
                         __ATOMIC_RELAXED, __HIP_MEMORY_SCOPE_AGENT);
    }
    asm volatile("s_waitcnt vmcnt(0)" ::: "memory");
    __syncthreads();
    if (tid == 0)
      __hip_atomic_store(flagg + o * 64, s + 1, __ATOMIC_RELEASE, __HIP_MEMORY_SCOPE_AGENT);
  }
}

// ---------------- emissions: em = concat(hf,hb) @ w_lin^T + b_lin ----------------
__global__ __launch_bounds__(256) void k_emis(const float* __restrict__ hf, const float* __restrict__ hb,
    const float* __restrict__ w_lin, const float* __restrict__ b_lin, float* __restrict__ em) {
  __shared__ float hsl[8][512];
  __shared__ float red[8][8][K_];
  const int tid = threadIdx.x;
  const int pos0 = blockIdx.x * 8;
  for (int it = 0; it < 4; ++it) {
    int idx = it * 256 + tid;
    int rr = idx >> 7, c4 = idx & 127;
    const float* src = (c4 < 64) ? (hf + ((size_t)(pos0 + rr)) * H_ + (c4 * 4))
                                 : (hb + ((size_t)(pos0 + rr)) * H_ + ((c4 - 64) * 4));
    float4 v = *(const float4*)src;
    *(float4*)&hsl[rr][c4 * 4] = v;
  }
  __syncthreads();
  const int k = tid & 31, jc = tid >> 5;
  float wreg[64];
#pragma unroll
  for (int i4 = 0; i4 < 16; ++i4) {
    float4 w = *(const float4*)(w_lin + (size_t)k * 512 + jc * 64 + i4 * 4);
    wreg[i4 * 4 + 0] = w.x; wreg[i4 * 4 + 1] = w.y; wreg[i4 * 4 + 2] = w.z; wreg[i4 * 4 + 3] = w.w;
  }
  float acc[8];
  for (int rr = 0; rr < 8; ++rr) {
    float a = 0.f;
#pragma unroll
    for (int i4 = 0; i4 < 16; ++i4) {
      float4 h = *(const float4*)&hsl[rr][jc * 64 + i4 * 4];
      a += wreg[i4 * 4 + 0] * h.x + wreg[i4 * 4 + 1] * h.y + wreg[i4 * 4 + 2] * h.z + wreg[i4 * 4 + 3] * h.w;
    }
    acc[rr] = a;
  }
  for (int rr2 = 0; rr2 < 8; ++rr2) red[rr2][jc][k] = acc[rr2];
  __syncthreads();
  {
    int rr = tid >> 5, kk = tid & 31;
    float s = b_lin[kk];
#pragma unroll
    for (int j = 0; j < 8; ++j) s += red[rr][j][kk];
    em[((size_t)(pos0 + rr)) * K_ + kk] = s;
  }
}

// ---------------- Viterbi ----------------
__global__ __launch_bounds__(64) void k_viterbi(const float* __restrict__ em,
    const int* __restrict__ lengths, const float* __restrict__ start_t,
    const float* __restrict__ end_t, const float* __restrict__ trans,
    int* __restrict__ out) {
  const int b = blockIdx.x;
  const int lane = threadIdx.x;
  __shared__ unsigned char hist[T_ - 1][K_];
  __shared__ float sl[K_];
  const int len = lengths[b];
  float tc[K_];
  float score = 0.f;
  if (lane < K_) {
#pragma unroll
    for (int i = 0; i < K_; ++i) tc[i] = trans[i * K_ + lane];
    score = start_t[lane] + em[((size_t)b * T_) * K_ + lane];
  }
  for (int t = 1; t < T_; ++t) {
    float emk = 0.f;
    if (lane < K_) {
      emk = em[((size_t)b * T_ + t) * K_ + lane];
      sl[lane] = score;
    }
    __syncthreads();
    if (lane < K_) {
      float best = sl[0] + tc[0]; int bi = 0;
#pragma unroll
      for (int i = 1; i < K_; ++i) {
        float c = sl[i] + tc[i];
        if (c > best) { best = c; bi = i; }
      }
      hist[t - 1][lane] = (unsigned char)bi;
      if (t < len) score = best + emk;
    }
    __syncthreads();
  }
  if (lane < K_) sl[lane] = score + end_t[lane];
  __syncthreads();
  int* outb = out + (size_t)b * T_;
  for (int t = lane; t < T_; t += 64)
    if (t >= len) outb[t] = 0;
  if (lane == 0) {
    float best = sl[0]; int cur = 0;
    for (int k2 = 1; k2 < K_; ++k2)
      if (sl[k2] > best) { best = sl[k2]; cur = k2; }
    outb[len - 1] = cur;
    for (int t = len - 2; t >= 0; --t) { cur = hist[t][cur]; outb[t] = cur; }
  }
}

extern "C" void kernel_launch(void* const* d_in, const int* in_sizes, int n_in,
                              void* d_out, int out_size, void* d_ws, size_t ws_size,
                              hipStream_t stream) {
  const int* tokens   = (const int*)d_in[0];
  const unsigned* maskw = (const unsigned*)d_in[1];
  const float* embed  = (const float*)d_in[2];
  const float* wih_f  = (const float*)d_in[3];
  const float* whh_f  = (const float*)d_in[4];
  const float* bih_f  = (const float*)d_in[5];
  const float* bhh_f  = (const float*)d_in[6];
  const float* wih_b  = (const float*)d_in[7];
  const float* whh_b  = (const float*)d_in[8];
  const float* bih_b  = (const float*)d_in[9];
  const float* bhh_b  = (const float*)d_in[10];
  const float* w_lin  = (const float*)d_in[11];
  const float* b_lin  = (const float*)d_in[12];
  const float* start_t = (const float*)d_in[13];
  const float* end_t  = (const float*)d_in[14];
  const float* trans  = (const float*)d_in[15];
  int* out = (int*)d_out;
  (void)in_sizes; (void)n_in; (void)out_size; (void)ws_size;

  char* ws = (char*)d_ws;
  size_t off = 0;
  auto alloc = [&](size_t bytes) { size_t o = off; off = (off + bytes + 255) & ~(size_t)255; return o; };
  int*   lengths = (int*)(ws + alloc((size_t)B_ * 4));
  float* wpk     = (float*)(ws + alloc((size_t)2 * 8 * 96 * 128 * 4 * 4));
  float* bias    = (float*)(ws + alloc((size_t)2 * G4H * 4));
  float* x       = (float*)(ws + alloc((size_t)B_ * T_ * E_ * 4));
  float* hf      = (float*)(ws + alloc((size_t)B_ * T_ * H_ * 4));
  float* hb      = (float*)(ws + alloc((size_t)B_ * T_ * H_ * 4));
  float* em      = (float*)(ws + alloc((size_t)B_ * T_ * K_ * 4));
  float* hx      = (float*)(ws + alloc((size_t)2 * 16 * 2 * 2048 * 4));
  int*   flags   = (int*)(ws + alloc((size_t)256 * 64 * 4));

  k_lengths<<<dim3(1), dim3(256), 0, stream>>>(maskw, lengths);
  k_packw2<<<dim3((2 * 8 * 96 * 128 * 4 + 255) / 256), dim3(256), 0, stream>>>(wih_f, whh_f, wih_b, whh_b, wpk);
  k_bias<<<dim3(8), dim3(256), 0, stream>>>(bih_f, bhh_f, bih_b, bhh_b, bias);
  k_gather<<<dim3((B_ * T_ * E_ / 4) / 256), dim3(256), 0, stream>>>(tokens, embed, x);
  k_zero<<<dim3(64), dim3(256), 0, stream>>>(flags);
  k_lstm2<<<dim3(256), dim3(512), 0, stream>>>(x, wpk, bias, hf, hb, hx, flags);
  k_emis<<<dim3(B_ * T_ / 8), dim3(256), 0, stream>>>(hf, hb, w_lin, b_lin, em);
  k_viterbi<<<dim3(B_), dim3(64), 0, stream>>>(em, lengths, start_t, end_t, trans, out);
}

// Round 6
// 3373.946 us; speedup vs baseline: 1.7777x; 1.0357x over previous
//
#include <hip/hip_runtime.h>
#include <hip/hip_bf16.h>

#define B_ 128
#define T_ 256
#define E_ 128
#define H_ 256
#define K_ 32
#define G4H 1024   // 4*H

__device__ __forceinline__ float sigf(float z) { return 1.0f / (1.0f + expf(-z)); }

// ---------------- mask dtype detect + lengths ----------------
__global__ void k_lengths(const unsigned* __restrict__ maskw, int* __restrict__ lengths) {
  __shared__ int flagBad;   // any word with value > 1  -> byte-packed bool
  __shared__ int flagOdd;   // any odd-indexed word nonzero -> not int64
  int tid = threadIdx.x;
  if (tid == 0) { flagBad = 0; flagOdd = 0; }
  __syncthreads();
  int bad = 0, odd = 0;
  for (int i = tid; i < (B_ * T_) / 4; i += 256) {
    unsigned v = maskw[i];
    if (v > 1u) bad = 1;
    if ((i & 1) && v) odd = 1;
  }
  if (bad) atomicOr(&flagBad, 1);
  if (odd) atomicOr(&flagOdd, 1);
  __syncthreads();
  int mode = flagBad ? 0 : (flagOdd ? 1 : 2);  // 0=bool8, 1=int32, 2=int64
  for (int b = tid; b < B_; b += 256) {
    int cnt = 0;
    if (mode == 0) {
      const unsigned char* mb = (const unsigned char*)maskw;
      for (int t = 0; t < T_; ++t) cnt += (mb[b * T_ + t] != 0);
    } else if (mode == 1) {
      for (int t = 0; t < T_; ++t) cnt += (maskw[b * T_ + t] != 0);
    } else {
      for (int t = 0; t < T_; ++t) cnt += (maskw[(size_t)(b * T_ + t) * 2] != 0);
    }
    if (cnt < 1) cnt = 1;
    lengths[b] = cnt;
  }
}

// ---------------- pack wih: wpkA[d][us][k4(32)][g(64)][4] ----------------
// g = ty*16 + u (ty in i,f,g,o; u = unit in 16-unit slice). brow = ty*256 + us*16 + u.
__global__ void k_packw3A(const float* __restrict__ wih_f, const float* __restrict__ wih_b,
                          float* __restrict__ wpkA) {
  int e = blockIdx.x * 256 + threadIdx.x;
  if (e >= 262144) return;
  int p  = e & 3;
  int g  = (e >> 2) & 63;
  int k4 = (e >> 8) & 31;
  int us = (e >> 13) & 15;
  int d  = (e >> 17) & 1;
  int brow = (g >> 4) * 256 + us * 16 + (g & 15);
  const float* wih = d ? wih_b : wih_f;
  wpkA[e] = wih[brow * E_ + k4 * 4 + p];
}

// ---------------- pack whh: wpkB[d][us][k4(64)][g(64)][4] ----------------
__global__ void k_packw3B(const float* __restrict__ whh_f, const float* __restrict__ whh_b,
                          float* __restrict__ wpkB) {
  int e = blockIdx.x * 256 + threadIdx.x;
  if (e >= 524288) return;
  int p  = e & 3;
  int g  = (e >> 2) & 63;
  int k4 = (e >> 8) & 63;
  int us = (e >> 14) & 15;
  int d  = (e >> 18) & 1;
  int brow = (g >> 4) * 256 + us * 16 + (g & 15);
  const float* whh = d ? whh_b : whh_f;
  wpkB[e] = whh[brow * H_ + k4 * 4 + p];
}

__global__ void k_bias(const float* __restrict__ bih_f, const float* __restrict__ bhh_f,
                       const float* __restrict__ bih_b, const float* __restrict__ bhh_b,
                       float* __restrict__ bias) {
  int e = blockIdx.x * 256 + threadIdx.x;
  if (e >= 2 * G4H) return;
  int d = e >> 10, j = e & 1023;
  bias[e] = d ? (bih_b[j] + bhh_b[j]) : (bih_f[j] + bhh_f[j]);
}

// ---------------- embedding gather ----------------
__global__ void k_gather(const int* __restrict__ tokens, const float* __restrict__ embed,
                         float* __restrict__ x) {
  int idx = blockIdx.x * 256 + threadIdx.x;   // float4 index
  int p = idx >> 5, e4 = idx & 31;
  int tok = tokens[p];
  ((float4*)x)[(size_t)p * 32 + e4] = ((const float4*)embed)[(size_t)tok * 32 + e4];
}

// ---------------- zero the sync flags (ws is poisoned each call) ----------------
__global__ void k_zero(int* __restrict__ flags) {
  int i = blockIdx.x * 256 + threadIdx.x;
  if (i < 16384) flags[i] = 0;
}

// ---------------- fused LSTM, full-chip, LDS-resident weights ----------------
// 256 WGs = 2 dirs x 8 rowgroups(16 rows) x 16 unit-slices(16 units = 64 gate rows).
// Weights (98 KB/WG) staged to LDS once; hot loop reads LDS only.
// Cross-WG h exchange per step via agent-scope relaxed atomics (L3) with
// per-WG release flags; hx double-buffered by step parity.
__global__ __launch_bounds__(512) void k_lstm3(const float* __restrict__ x,
    const float* __restrict__ wpkA, const float* __restrict__ wpkB,
    const float* __restrict__ bias,
    float* __restrict__ hf, float* __restrict__ hb,
    float* __restrict__ hx, int* __restrict__ flags) {
  const int wg = blockIdx.x;          // 0..255
  const int us = wg & 15;             // unit slice
  const int rb = (wg >> 4) & 7;       // row group
  const int d  = wg >> 7;             // dir
  const int b0 = rb * 16;
  const int tid = threadIdx.x;
  __shared__ float4 wA[32 * 64];      // [k4][g] wih slice
  __shared__ float4 wB[64 * 64];      // [k4][g] whh slice
  __shared__ float4 vL[96 * 16];      // [k4][r]: k4 0..31 = x, 32..95 = h
  __shared__ float  gbuf[64 * 16];    // [g][r]

  // stage weights once
  {
    const float4* srcA = (const float4*)(wpkA + (size_t)(d * 16 + us) * 8192);
    for (int i = tid; i < 2048; i += 512) wA[i] = srcA[i];
    const float4* srcB = (const float4*)(wpkB + (size_t)(d * 16 + us) * 16384);
    for (int i = tid; i < 4096; i += 512) wB[i] = srcB[i];
  }
  const int r  = tid & 15;
  const int gg = tid >> 4;            // 0..31
  const int g0 = gg, g1 = gg + 32;
  const float bj0 = bias[d * G4H + (g0 >> 4) * 256 + us * 16 + (g0 & 15)];
  const float bj1 = bias[d * G4H + (g1 >> 4) * 256 + us * 16 + (g1 & 15)];
  float* __restrict__ hout = d ? hb : hf;
  float* __restrict__ hxg = hx + (size_t)(d * 8 + rb) * 8192;   // [par][u4g 64][r 16][4]
  int* __restrict__ flagg = flags + (d * 8 + rb) * 16 * 64;     // 16 flags, stride 64
  // x-stage role
  const int sk4 = tid >> 4, sr = tid & 15;
  float c0 = 0.f, c1 = 0.f, c2 = 0.f, c3 = 0.f;   // cell state (tid<64 roles)
  float4 xr;
  {
    int t0 = d ? (T_ - 1) : 0;
    xr = *(const float4*)(x + ((size_t)(b0 + sr) * T_ + t0) * E_ + sk4 * 4);
  }
  __syncthreads();   // weights staged

  for (int s = 0; s < T_; ++s) {
    const int t = d ? (T_ - 1 - s) : s;
    if (s > 0 && tid < 16) {
      int* fp = flagg + tid * 64;
      while (__hip_atomic_load(fp, __ATOMIC_RELAXED, __HIP_MEMORY_SCOPE_AGENT) < s) {}
    }
    __syncthreads();   // h ready in hx; vL free (prev GEMM done)
    // x part of vL (prefetched into xr)
    vL[sk4 * 16 + sr] = xr;
    // h part of vL
    if (s == 0) {
      for (int i = tid; i < 1024; i += 512) vL[512 + i] = make_float4(0.f, 0.f, 0.f, 0.f);
    } else {
      const float* hsrc = hxg + (size_t)(s & 1) * 4096;
      int i0 = tid, i1 = tid + 512;
      float4 v0, v1;
      v0.x = __hip_atomic_load(hsrc + i0 * 4 + 0, __ATOMIC_RELAXED, __HIP_MEMORY_SCOPE_AGENT);
      v0.y = __hip_atomic_load(hsrc + i0 * 4 + 1, __ATOMIC_RELAXED, __HIP_MEMORY_SCOPE_AGENT);
      v0.z = __hip_atomic_load(hsrc + i0 * 4 + 2, __ATOMIC_RELAXED, __HIP_MEMORY_SCOPE_AGENT);
      v0.w = __hip_atomic_load(hsrc + i0 * 4 + 3, __ATOMIC_RELAXED, __HIP_MEMORY_SCOPE_AGENT);
      v1.x = __hip_atomic_load(hsrc + i1 * 4 + 0, __ATOMIC_RELAXED, __HIP_MEMORY_SCOPE_AGENT);
      v1.y = __hip_atomic_load(hsrc + i1 * 4 + 1, __ATOMIC_RELAXED, __HIP_MEMORY_SCOPE_AGENT);
      v1.z = __hip_atomic_load(hsrc + i1 * 4 + 2, __ATOMIC_RELAXED, __HIP_MEMORY_SCOPE_AGENT);
      v1.w = __hip_atomic_load(hsrc + i1 * 4 + 3, __ATOMIC_RELAXED, __HIP_MEMORY_SCOPE_AGENT);
      vL[512 + i0] = v0;
      vL[512 + i1] = v1;
    }
    __syncthreads();   // vL complete
    // prefetch next x into regs (hidden under GEMM)
    if (s + 1 < T_) {
      int tn = d ? (T_ - 2 - s) : (s + 1);
      xr = *(const float4*)(x + ((size_t)(b0 + sr) * T_ + tn) * E_ + sk4 * 4);
    }
    // GEMM from LDS: thread owns gates (g0,r) and (g1,r)
    float a0 = bj0, a1 = bj1;
#pragma unroll 4
    for (int k4 = 0; k4 < 32; ++k4) {
      float4 v  = vL[k4 * 16 + r];
      float4 wa = wA[k4 * 64 + g0];
      float4 wb = wA[k4 * 64 + g1];
      a0 += wa.x * v.x + wa.y * v.y + wa.z * v.z + wa.w * v.w;
      a1 += wb.x * v.x + wb.y * v.y + wb.z * v.z + wb.w * v.w;
    }
#pragma unroll 4
    for (int k4 = 0; k4 < 64; ++k4) {
      float4 v  = vL[(32 + k4) * 16 + r];
      float4 wa = wB[k4 * 64 + g0];
      float4 wb = wB[k4 * 64 + g1];
      a0 += wa.x * v.x + wa.y * v.y + wa.z * v.z + wa.w * v.w;
      a1 += wb.x * v.x + wb.y * v.y + wb.z * v.z + wb.w * v.w;
    }
    gbuf[g0 * 16 + r] = a0;
    gbuf[g1 * 16 + r] = a1;
    __syncthreads();   // gbuf ready, all vL reads done
    // cell update: tid<64 -> (u4 = tid>>4: 4 units, ur = tid&15: row)
    if (tid < 64) {
      const int u4 = tid >> 4, ur = tid & 15;
      const int u = u4 * 4;
      float ig0 = gbuf[(u + 0) * 16 + ur], fg0 = gbuf[(16 + u + 0) * 16 + ur];
      float gg0 = gbuf[(32 + u + 0) * 16 + ur], og0 = gbuf[(48 + u + 0) * 16 + ur];
      float ig1 = gbuf[(u + 1) * 16 + ur], fg1 = gbuf[(16 + u + 1) * 16 + ur];
      float gg1 = gbuf[(32 + u + 1) * 16 + ur], og1 = gbuf[(48 + u + 1) * 16 + ur];
      float ig2 = gbuf[(u + 2) * 16 + ur], fg2 = gbuf[(16 + u + 2) * 16 + ur];
      float gg2 = gbuf[(32 + u + 2) * 16 + ur], og2 = gbuf[(48 + u + 2) * 16 + ur];
      float ig3 = gbuf[(u + 3) * 16 + ur], fg3 = gbuf[(16 + u + 3) * 16 + ur];
      float gg3 = gbuf[(32 + u + 3) * 16 + ur], og3 = gbuf[(48 + u + 3) * 16 + ur];
      c0 = sigf(fg0) * c0 + sigf(ig0) * tanhf(gg0);
      c1 = sigf(fg1) * c1 + sigf(ig1) * tanhf(gg1);
      c2 = sigf(fg2) * c2 + sigf(ig2) * tanhf(gg2);
      c3 = sigf(fg3) * c3 + sigf(ig3) * tanhf(gg3);
      float hn0 = sigf(og0) * tanhf(c0);
      float hn1 = sigf(og1) * tanhf(c1);
      float hn2 = sigf(og2) * tanhf(c2);
      float hn3 = sigf(og3) * tanhf(c3);
      float4 ho = make_float4(hn0, hn1, hn2, hn3);
      *(float4*)(hout + ((size_t)(b0 + ur) * T_ + t) * H_ + us * 16 + u4 * 4) = ho;
      float* hdst = hxg + (size_t)((s + 1) & 1) * 4096 + ((us * 4 + u4) * 16 + ur) * 4;
      __hip_atomic_store(hdst + 0, hn0, __ATOMIC_RELAXED, __HIP_MEMORY_SCOPE_AGENT);
      __hip_atomic_store(hdst + 1, hn1, __ATOMIC_RELAXED, __HIP_MEMORY_SCOPE_AGENT);
      __hip_atomic_store(hdst + 2, hn2, __ATOMIC_RELAXED, __HIP_MEMORY_SCOPE_AGENT);
      __hip_atomic_store(hdst + 3, hn3, __ATOMIC_RELAXED, __HIP_MEMORY_SCOPE_AGENT);
    }
    asm volatile("s_waitcnt vmcnt(0)" ::: "memory");
    __syncthreads();
    if (tid == 0)
      __hip_atomic_store(flagg + us * 64, s + 1, __ATOMIC_RELEASE, __HIP_MEMORY_SCOPE_AGENT);
  }
}

// ---------------- emissions: em = concat(hf,hb) @ w_lin^T + b_lin ----------------
__global__ __launch_bounds__(256) void k_emis(const float* __restrict__ hf, const float* __restrict__ hb,
    const float* __restrict__ w_lin, const float* __restrict__ b_lin, float* __restrict__ em) {
  __shared__ float hsl[8][512];
  __shared__ float red[8][8][K_];
  const int tid = threadIdx.x;
  const int pos0 = blockIdx.x * 8;
  for (int it = 0; it < 4; ++it) {
    int idx = it * 256 + tid;
    int rr = idx >> 7, c4 = idx & 127;
    const float* src = (c4 < 64) ? (hf + ((size_t)(pos0 + rr)) * H_ + (c4 * 4))
                                 : (hb + ((size_t)(pos0 + rr)) * H_ + ((c4 - 64) * 4));
    float4 v = *(const float4*)src;
    *(float4*)&hsl[rr][c4 * 4] = v;
  }
  __syncthreads();
  const int k = tid & 31, jc = tid >> 5;
  float wreg[64];
#pragma unroll
  for (int i4 = 0; i4 < 16; ++i4) {
    float4 w = *(const float4*)(w_lin + (size_t)k * 512 + jc * 64 + i4 * 4);
    wreg[i4 * 4 + 0] = w.x; wreg[i4 * 4 + 1] = w.y; wreg[i4 * 4 + 2] = w.z; wreg[i4 * 4 + 3] = w.w;
  }
  float acc[8];
  for (int rr = 0; rr < 8; ++rr) {
    float a = 0.f;
#pragma unroll
    for (int i4 = 0; i4 < 16; ++i4) {
      float4 h = *(const float4*)&hsl[rr][jc * 64 + i4 * 4];
      a += wreg[i4 * 4 + 0] * h.x + wreg[i4 * 4 + 1] * h.y + wreg[i4 * 4 + 2] * h.z + wreg[i4 * 4 + 3] * h.w;
    }
    acc[rr] = a;
  }
  for (int rr2 = 0; rr2 < 8; ++rr2) red[rr2][jc][k] = acc[rr2];
  __syncthreads();
  {
    int rr = tid >> 5, kk = tid & 31;
    float s = b_lin[kk];
#pragma unroll
    for (int j = 0; j < 8; ++j) s += red[rr][j][kk];
    em[((size_t)(pos0 + rr)) * K_ + kk] = s;
  }
}

// ---------------- Viterbi ----------------
__global__ __launch_bounds__(64) void k_viterbi(const float* __restrict__ em,
    const int* __restrict__ lengths, const float* __restrict__ start_t,
    const float* __restrict__ end_t, const float* __restrict__ trans,
    int* __restrict__ out) {
  const int b = blockIdx.x;
  const int lane = threadIdx.x;
  __shared__ unsigned char hist[T_ - 1][K_];
  __shared__ float sl[K_];
  const int len = lengths[b];
  float tc[K_];
  float score = 0.f;
  if (lane < K_) {
#pragma unroll
    for (int i = 0; i < K_; ++i) tc[i] = trans[i * K_ + lane];
    score = start_t[lane] + em[((size_t)b * T_) * K_ + lane];
  }
  for (int t = 1; t < T_; ++t) {
    float emk = 0.f;
    if (lane < K_) {
      emk = em[((size_t)b * T_ + t) * K_ + lane];
      sl[lane] = score;
    }
    __syncthreads();
    if (lane < K_) {
      float best = sl[0] + tc[0]; int bi = 0;
#pragma unroll
      for (int i = 1; i < K_; ++i) {
        float c = sl[i] + tc[i];
        if (c > best) { best = c; bi = i; }
      }
      hist[t - 1][lane] = (unsigned char)bi;
      if (t < len) score = best + emk;
    }
    __syncthreads();
  }
  if (lane < K_) sl[lane] = score + end_t[lane];
  __syncthreads();
  int* outb = out + (size_t)b * T_;
  for (int t = lane; t < T_; t += 64)
    if (t >= len) outb[t] = 0;
  if (lane == 0) {
    float best = sl[0]; int cur = 0;
    for (int k2 = 1; k2 < K_; ++k2)
      if (sl[k2] > best) { best = sl[k2]; cur = k2; }
    outb[len - 1] = cur;
    for (int t = len - 2; t >= 0; --t) { cur = hist[t][cur]; outb[t] = cur; }
  }
}

extern "C" void kernel_launch(void* const* d_in, const int* in_sizes, int n_in,
                              void* d_out, int out_size, void* d_ws, size_t ws_size,
                              hipStream_t stream) {
  const int* tokens   = (const int*)d_in[0];
  const unsigned* maskw = (const unsigned*)d_in[1];
  const float* embed  = (const float*)d_in[2];
  const float* wih_f  = (const float*)d_in[3];
  const float* whh_f  = (const float*)d_in[4];
  const float* bih_f  = (const float*)d_in[5];
  const float* bhh_f  = (const float*)d_in[6];
  const float* wih_b  = (const float*)d_in[7];
  const float* whh_b  = (const float*)d_in[8];
  const float* bih_b  = (const float*)d_in[9];
  const float* bhh_b  = (const float*)d_in[10];
  const float* w_lin  = (const float*)d_in[11];
  const float* b_lin  = (const float*)d_in[12];
  const float* start_t = (const float*)d_in[13];
  const float* end_t  = (const float*)d_in[14];
  const float* trans  = (const float*)d_in[15];
  int* out = (int*)d_out;
  (void)in_sizes; (void)n_in; (void)out_size; (void)ws_size;

  char* ws = (char*)d_ws;
  size_t off = 0;
  auto alloc = [&](size_t bytes) { size_t o = off; off = (off + bytes + 255) & ~(size_t)255; return o; };
  int*   lengths = (int*)(ws + alloc((size_t)B_ * 4));
  float* wpkA    = (float*)(ws + alloc((size_t)262144 * 4));
  float* wpkB    = (float*)(ws + alloc((size_t)524288 * 4));
  float* bias    = (float*)(ws + alloc((size_t)2 * G4H * 4));
  float* x       = (float*)(ws + alloc((size_t)B_ * T_ * E_ * 4));
  float* hf      = (float*)(ws + alloc((size_t)B_ * T_ * H_ * 4));
  float* hb      = (float*)(ws + alloc((size_t)B_ * T_ * H_ * 4));
  float* em      = (float*)(ws + alloc((size_t)B_ * T_ * K_ * 4));
  float* hx      = (float*)(ws + alloc((size_t)16 * 8192 * 4));
  int*   flags   = (int*)(ws + alloc((size_t)16384 * 4));

  k_lengths<<<dim3(1), dim3(256), 0, stream>>>(maskw, lengths);
  k_packw3A<<<dim3(1024), dim3(256), 0, stream>>>(wih_f, wih_b, wpkA);
  k_packw3B<<<dim3(2048), dim3(256), 0, stream>>>(whh_f, whh_b, wpkB);
  k_bias<<<dim3(8), dim3(256), 0, stream>>>(bih_f, bhh_f, bih_b, bhh_b, bias);
  k_gather<<<dim3((B_ * T_ * E_ / 4) / 256), dim3(256), 0, stream>>>(tokens, embed, x);
  k_zero<<<dim3(64), dim3(256), 0, stream>>>(flags);
  k_lstm3<<<dim3(256), dim3(512), 0, stream>>>(x, wpkA, wpkB, bias, hf, hb, hx, flags);
  k_emis<<<dim3(B_ * T_ / 8), dim3(256), 0, stream>>>(hf, hb, w_lin, b_lin, em);
  k_viterbi<<<dim3(B_), dim3(64), 0, stream>>>(em, lengths, start_t, end_t, trans, out);
}

// Round 8
// 3179.687 us; speedup vs baseline: 1.8864x; 1.0611x over previous
//
#include <hip/hip_runtime.h>
#include <hip/hip_bf16.h>

#define B_ 128
#define T_ 256
#define E_ 128
#define H_ 256
#define K_ 32
#define G4H 1024   // 4*H

__device__ __forceinline__ float sigf(float z) { return 1.0f / (1.0f + expf(-z)); }

// ---------------- mask dtype detect + lengths ----------------
__global__ void k_lengths(const unsigned* __restrict__ maskw, int* __restrict__ lengths) {
  __shared__ int flagBad;
  __shared__ int flagOdd;
  int tid = threadIdx.x;
  if (tid == 0) { flagBad = 0; flagOdd = 0; }
  __syncthreads();
  int bad = 0, odd = 0;
  for (int i = tid; i < (B_ * T_) / 4; i += 256) {
    unsigned v = maskw[i];
    if (v > 1u) bad = 1;
    if ((i & 1) && v) odd = 1;
  }
  if (bad) atomicOr(&flagBad, 1);
  if (odd) atomicOr(&flagOdd, 1);
  __syncthreads();
  int mode = flagBad ? 0 : (flagOdd ? 1 : 2);  // 0=bool8, 1=int32, 2=int64
  for (int b = tid; b < B_; b += 256) {
    int cnt = 0;
    if (mode == 0) {
      const unsigned char* mb = (const unsigned char*)maskw;
      for (int t = 0; t < T_; ++t) cnt += (mb[b * T_ + t] != 0);
    } else if (mode == 1) {
      for (int t = 0; t < T_; ++t) cnt += (maskw[b * T_ + t] != 0);
    } else {
      for (int t = 0; t < T_; ++t) cnt += (maskw[(size_t)(b * T_ + t) * 2] != 0);
    }
    if (cnt < 1) cnt = 1;
    lengths[b] = cnt;
  }
}

// ---------------- pack combined weights: wpk[d][us][k4(96)][g(64)][4] ----------------
// g = ty*16 + u; brow = ty*256 + us*16 + u; k = k4*4+p over concat(x[128], h[256]).
__global__ void k_packw4(const float* __restrict__ wih_f, const float* __restrict__ whh_f,
                         const float* __restrict__ wih_b, const float* __restrict__ whh_b,
                         float* __restrict__ wpk) {
  int e = blockIdx.x * 256 + threadIdx.x;
  if (e >= 786432) return;
  int p = e & 3;
  int g = (e >> 2) & 63;
  int rest = e >> 8;
  int k4 = rest % 96;
  int dus = rest / 96;
  int us = dus & 15, d = dus >> 4;
  int brow = (g >> 4) * 256 + us * 16 + (g & 15);
  int k = k4 * 4 + p;
  const float* wih = d ? wih_b : wih_f;
  const float* whh = d ? whh_b : whh_f;
  wpk[e] = (k < E_) ? wih[brow * E_ + k] : whh[brow * H_ + (k - E_)];
}

__global__ void k_bias(const float* __restrict__ bih_f, const float* __restrict__ bhh_f,
                       const float* __restrict__ bih_b, const float* __restrict__ bhh_b,
                       float* __restrict__ bias) {
  int e = blockIdx.x * 256 + threadIdx.x;
  if (e >= 2 * G4H) return;
  int d = e >> 10, j = e & 1023;
  bias[e] = d ? (bih_b[j] + bhh_b[j]) : (bih_f[j] + bhh_f[j]);
}

// ---------------- embedding gather ----------------
__global__ void k_gather(const int* __restrict__ tokens, const float* __restrict__ embed,
                         float* __restrict__ x) {
  int idx = blockIdx.x * 256 + threadIdx.x;
  int p = idx >> 5, e4 = idx & 31;
  int tok = tokens[p];
  ((float4*)x)[(size_t)p * 32 + e4] = ((const float4*)embed)[(size_t)tok * 32 + e4];
}

// ---------------- zero sync flags ----------------
__global__ void k_zero(int* __restrict__ flags) {
  int i = blockIdx.x * 256 + threadIdx.x;
  if (i < 16384) flags[i] = 0;
}

// ---------------- fused LSTM v4: k-split + 2x2 tiles ----------------
// 256 WGs = 2 dirs x 8 rowgroups(16 rows) x 16 unit-slices(16 units = 64 gate rows).
// 512 thr = 2 k-halves x (32 gate-pairs x 8 row-pairs). Per k4: 4 ds_read_b128 : 16 FMA.
// Weights LDS-resident (96 KB). Partials reduced via padded gbuf2. Exchange = R6 scheme.
__global__ __launch_bounds__(512) void k_lstm4(const float* __restrict__ x,
    const float* __restrict__ wpk, const float* __restrict__ bias,
    float* __restrict__ hf, float* __restrict__ hb,
    float* __restrict__ hx, int* __restrict__ flags) {
  const int wg = blockIdx.x;
  const int us = wg & 15;
  const int rb = (wg >> 4) & 7;
  const int d  = wg >> 7;
  const int b0 = rb * 16;
  const int tid = threadIdx.x;
  __shared__ float4 wL[96 * 64];      // [k4][g] 96 KB
  __shared__ float4 vL[96 * 16];      // [k4][r] 24 KB (k4 0..31 = x, 32..95 = h)
  __shared__ float  gbuf2[2 * 64 * 17];  // [kc][g][17pad]

  // stage weights once (12 float4 per thread)
  {
    const float4* wsrc = (const float4*)(wpk + (size_t)(d * 16 + us) * 24576);
    for (int i = tid; i < 6144; i += 512) wL[i] = wsrc[i];
  }
  // roles
  const int r2 = tid & 7;             // row pair
  const int gg = (tid >> 3) & 31;     // gate pair
  const int kc = tid >> 8;            // k half
  const int g0 = 2 * gg, g1 = g0 + 1;
  const int uu = tid & 15, rr = (tid >> 4) & 15;   // cell role (tid<256)
  const int sk4 = tid >> 4, sr = tid & 15;         // x-stage role
  float b_i = 0.f, b_f = 0.f, b_g = 0.f, b_o = 0.f;
  if (tid < 256) {
    b_i = bias[d * G4H + 0 * 256 + us * 16 + uu];
    b_f = bias[d * G4H + 1 * 256 + us * 16 + uu];
    b_g = bias[d * G4H + 2 * 256 + us * 16 + uu];
    b_o = bias[d * G4H + 3 * 256 + us * 16 + uu];
  }
  float creg = 0.f;
  float4 xr;
  {
    int t0 = d ? (T_ - 1) : 0;
    xr = *(const float4*)(x + ((size_t)(b0 + sr) * T_ + t0) * E_ + sk4 * 4);
  }
  float* __restrict__ hout = d ? hb : hf;
  float* __restrict__ hxg = hx + (size_t)(d * 8 + rb) * 8192;  // [par][256u][16r]
  int* __restrict__ flagg = flags + (d * 8 + rb) * 1024;       // 16 flags stride 64
  __syncthreads();   // weights staged

  for (int s = 0; s < T_; ++s) {
    const int t = d ? (T_ - 1 - s) : s;
    if (s > 0 && tid < 16) {
      int* fp = flagg + tid * 64;
      while (__hip_atomic_load(fp, __ATOMIC_RELAXED, __HIP_MEMORY_SCOPE_AGENT) < s) {}
    }
    __syncthreads();   // h ready in hx; vL free (prev GEMM done)
    // x part of vL (prefetched in xr)
    vL[sk4 * 16 + sr] = xr;
    // h part of vL: linear read of hxg, transposed scatter into float4-over-k layout
    if (s == 0) {
#pragma unroll
      for (int it = 0; it < 8; ++it) {
        int i = it * 512 + tid;
        ((float*)vL)[(32 + (i >> 6)) * 64 + (i & 15) * 4 + ((i >> 4) & 3)] = 0.f;
      }
    } else {
      const float* hsrc = hxg + (size_t)(s & 1) * 4096;
#pragma unroll
      for (int it = 0; it < 8; ++it) {
        int i = it * 512 + tid;
        float hv = __hip_atomic_load(hsrc + i, __ATOMIC_RELAXED, __HIP_MEMORY_SCOPE_AGENT);
        ((float*)vL)[(32 + (i >> 6)) * 64 + (i & 15) * 4 + ((i >> 4) & 3)] = hv;
      }
    }
    __syncthreads();   // vL complete
    // prefetch next x (hidden under GEMM)
    if (s + 1 < T_) {
      int tn = d ? (T_ - 2 - s) : (s + 1);
      xr = *(const float4*)(x + ((size_t)(b0 + sr) * T_ + tn) * E_ + sk4 * 4);
    }
    // GEMM: thread = (kc, 2 gates g0/g1, 2 rows 2r2/2r2+1) over its 48 k4
    float a00 = 0.f, a01 = 0.f, a10 = 0.f, a11 = 0.f;
    {
      const float4* wp = wL + kc * 48 * 64;
      const float4* vp = vL + kc * 48 * 16;
#pragma unroll 4
      for (int k4 = 0; k4 < 48; ++k4) {
        float4 w0 = wp[k4 * 64 + g0];
        float4 w1 = wp[k4 * 64 + g1];
        float4 v0 = vp[k4 * 16 + 2 * r2];
        float4 v1 = vp[k4 * 16 + 2 * r2 + 1];
        a00 += w0.x * v0.x + w0.y * v0.y + w0.z * v0.z + w0.w * v0.w;
        a01 += w0.x * v1.x + w0.y * v1.y + w0.z * v1.z + w0.w * v1.w;
        a10 += w1.x * v0.x + w1.y * v0.y + w1.z * v0.z + w1.w * v0.w;
        a11 += w1.x * v1.x + w1.y * v1.y + w1.z * v1.z + w1.w * v1.w;
      }
    }
    gbuf2[kc * 1088 + g0 * 17 + 2 * r2]     = a00;
    gbuf2[kc * 1088 + g0 * 17 + 2 * r2 + 1] = a01;
    gbuf2[kc * 1088 + g1 * 17 + 2 * r2]     = a10;
    gbuf2[kc * 1088 + g1 * 17 + 2 * r2 + 1] = a11;
    __syncthreads();   // partials ready
    // cell update: tid<256 -> (unit uu, row rr)
    if (tid < 256) {
      float ig = gbuf2[uu * 17 + rr]        + gbuf2[1088 + uu * 17 + rr]        + b_i;
      float fg = gbuf2[(16 + uu) * 17 + rr] + gbuf2[1088 + (16 + uu) * 17 + rr] + b_f;
      float gv = gbuf2[(32 + uu) * 17 + rr] + gbuf2[1088 + (32 + uu) * 17 + rr] + b_g;
      float og = gbuf2[(48 + uu) * 17 + rr] + gbuf2[1088 + (48 + uu) * 17 + rr] + b_o;
      creg = sigf(fg) * creg + sigf(ig) * tanhf(gv);
      float hn = sigf(og) * tanhf(creg);
      hout[((size_t)(b0 + rr) * T_ + t) * H_ + us * 16 + uu] = hn;
      __hip_atomic_store(hxg + (size_t)((s + 1) & 1) * 4096 + (us * 16 + uu) * 16 + rr, hn,
                         __ATOMIC_RELAXED, __HIP_MEMORY_SCOPE_AGENT);
    }
    asm volatile("s_waitcnt vmcnt(0)" ::: "memory");
    __syncthreads();
    if (tid == 0)
      __hip_atomic_store(flagg + us * 64, s + 1, __ATOMIC_RELEASE, __HIP_MEMORY_SCOPE_AGENT);
  }
}

// ---------------- emissions: em = concat(hf,hb) @ w_lin^T + b_lin ----------------
__global__ __launch_bounds__(256) void k_emis(const float* __restrict__ hf, const float* __restrict__ hb,
    const float* __restrict__ w_lin, const float* __restrict__ b_lin, float* __restrict__ em) {
  __shared__ float hsl[8][512];
  __shared__ float red[8][8][K_];
  const int tid = threadIdx.x;
  const int pos0 = blockIdx.x * 8;
  for (int it = 0; it < 4; ++it) {
    int idx = it * 256 + tid;
    int rr = idx >> 7, c4 = idx & 127;
    const float* src = (c4 < 64) ? (hf + ((size_t)(pos0 + rr)) * H_ + (c4 * 4))
                                 : (hb + ((size_t)(pos0 + rr)) * H_ + ((c4 - 64) * 4));
    float4 v = *(const float4*)src;
    *(float4*)&hsl[rr][c4 * 4] = v;
  }
  __syncthreads();
  const int k = tid & 31, jc = tid >> 5;
  float wreg[64];
#pragma unroll
  for (int i4 = 0; i4 < 16; ++i4) {
    float4 w = *(const float4*)(w_lin + (size_t)k * 512 + jc * 64 + i4 * 4);
    wreg[i4 * 4 + 0] = w.x; wreg[i4 * 4 + 1] = w.y; wreg[i4 * 4 + 2] = w.z; wreg[i4 * 4 + 3] = w.w;
  }
  float acc[8];
  for (int rr = 0; rr < 8; ++rr) {
    float a = 0.f;
#pragma unroll
    for (int i4 = 0; i4 < 16; ++i4) {
      float4 h = *(const float4*)&hsl[rr][jc * 64 + i4 * 4];
      a += wreg[i4 * 4 + 0] * h.x + wreg[i4 * 4 + 1] * h.y + wreg[i4 * 4 + 2] * h.z + wreg[i4 * 4 + 3] * h.w;
    }
    acc[rr] = a;
  }
  for (int rr2 = 0; rr2 < 8; ++rr2) red[rr2][jc][k] = acc[rr2];
  __syncthreads();
  {
    int rr = tid >> 5, kk = tid & 31;
    float s = b_lin[kk];
#pragma unroll
    for (int j = 0; j < 8; ++j) s += red[rr][j][kk];
    em[((size_t)(pos0 + rr)) * K_ + kk] = s;
  }
}

// ---------------- Viterbi ----------------
__global__ __launch_bounds__(64) void k_viterbi(const float* __restrict__ em,
    const int* __restrict__ lengths, const float* __restrict__ start_t,
    const float* __restrict__ end_t, const float* __restrict__ trans,
    int* __restrict__ out) {
  const int b = blockIdx.x;
  const int lane = threadIdx.x;
  __shared__ unsigned char hist[T_ - 1][K_];
  __shared__ float sl[K_];
  const int len = lengths[b];
  float tc[K_];
  float score = 0.f;
  if (lane < K_) {
#pragma unroll
    for (int i = 0; i < K_; ++i) tc[i] = trans[i * K_ + lane];
    score = start_t[lane] + em[((size_t)b * T_) * K_ + lane];
  }
  for (int t = 1; t < T_; ++t) {
    float emk = 0.f;
    if (lane < K_) {
      emk = em[((size_t)b * T_ + t) * K_ + lane];
      sl[lane] = score;
    }
    __syncthreads();
    if (lane < K_) {
      float best = sl[0] + tc[0]; int bi = 0;
#pragma unroll
      for (int i = 1; i < K_; ++i) {
        float c = sl[i] + tc[i];
        if (c > best) { best = c; bi = i; }
      }
      hist[t - 1][lane] = (unsigned char)bi;
      if (t < len) score = best + emk;
    }
    __syncthreads();
  }
  if (lane < K_) sl[lane] = score + end_t[lane];
  __syncthreads();
  int* outb = out + (size_t)b * T_;
  for (int t = lane; t < T_; t += 64)
    if (t >= len) outb[t] = 0;
  if (lane == 0) {
    float best = sl[0]; int cur = 0;
    for (int k2 = 1; k2 < K_; ++k2)
      if (sl[k2] > best) { best = sl[k2]; cur = k2; }
    outb[len - 1] = cur;
    for (int t = len - 2; t >= 0; --t) { cur = hist[t][cur]; outb[t] = cur; }
  }
}

extern "C" void kernel_launch(void* const* d_in, const int* in_sizes, int n_in,
                              void* d_out, int out_size, void* d_ws, size_t ws_size,
                              hipStream_t stream) {
  const int* tokens   = (const int*)d_in[0];
  const unsigned* maskw = (const unsigned*)d_in[1];
  const float* embed  = (const float*)d_in[2];
  const float* wih_f  = (const float*)d_in[3];
  const float* whh_f  = (const float*)d_in[4];
  const float* bih_f  = (const float*)d_in[5];
  const float* bhh_f  = (const float*)d_in[6];
  const float* wih_b  = (const float*)d_in[7];
  const float* whh_b  = (const float*)d_in[8];
  const float* bih_b  = (const float*)d_in[9];
  const float* bhh_b  = (const float*)d_in[10];
  const float* w_lin  = (const float*)d_in[11];
  const float* b_lin  = (const float*)d_in[12];
  const float* start_t = (const float*)d_in[13];
  const float* end_t  = (const float*)d_in[14];
  const float* trans  = (const float*)d_in[15];
  int* out = (int*)d_out;
  (void)in_sizes; (void)n_in; (void)out_size; (void)ws_size;

  char* ws = (char*)d_ws;
  size_t off = 0;
  auto alloc = [&](size_t bytes) { size_t o = off; off = (off + bytes + 255) & ~(size_t)255; return o; };
  int*   lengths = (int*)(ws + alloc((size_t)B_ * 4));
  float* wpk     = (float*)(ws + alloc((size_t)786432 * 4));
  float* bias    = (float*)(ws + alloc((size_t)2 * G4H * 4));
  float* x       = (float*)(ws + alloc((size_t)B_ * T_ * E_ * 4));
  float* hf      = (float*)(ws + alloc((size_t)B_ * T_ * H_ * 4));
  float* hb      = (float*)(ws + alloc((size_t)B_ * T_ * H_ * 4));
  float* em      = (float*)(ws + alloc((size_t)B_ * T_ * K_ * 4));
  float* hx      = (float*)(ws + alloc((size_t)16 * 8192 * 4));
  int*   flags   = (int*)(ws + alloc((size_t)16384 * 4));

  k_lengths<<<dim3(1), dim3(256), 0, stream>>>(maskw, lengths);
  k_packw4<<<dim3(3072), dim3(256), 0, stream>>>(wih_f, whh_f, wih_b, whh_b, wpk);
  k_bias<<<dim3(8), dim3(256), 0, stream>>>(bih_f, bhh_f, bih_b, bhh_b, bias);
  k_gather<<<dim3((B_ * T_ * E_ / 4) / 256), dim3(256), 0, stream>>>(tokens, embed, x);
  k_zero<<<dim3(64), dim3(256), 0, stream>>>(flags);
  k_lstm4<<<dim3(256), dim3(512), 0, stream>>>(x, wpk, bias, hf, hb, hx, flags);
  k_emis<<<dim3(B_ * T_ / 8), dim3(256), 0, stream>>>(hf, hb, w_lin, b_lin, em);
  k_viterbi<<<dim3(B_), dim3(64), 0, stream>>>(em, lengths, start_t, end_t, trans, out);
}

// Round 11
// 3058.300 us; speedup vs baseline: 1.9612x; 1.0397x over previous
//
#include <hip/hip_runtime.h>
#include <hip/hip_bf16.h>

#define B_ 128
#define T_ 256
#define E_ 128
#define H_ 256
#define K_ 32
#define G4H 1024   // 4*H

__device__ __forceinline__ float sigf(float z) { return 1.0f / (1.0f + expf(-z)); }

// ---------------- mask dtype detect + lengths ----------------
__global__ void k_lengths(const unsigned* __restrict__ maskw, int* __restrict__ lengths) {
  __shared__ int flagBad;
  __shared__ int flagOdd;
  int tid = threadIdx.x;
  if (tid == 0) { flagBad = 0; flagOdd = 0; }
  __syncthreads();
  int bad = 0, odd = 0;
  for (int i = tid; i < (B_ * T_) / 4; i += 256) {
    unsigned v = maskw[i];
    if (v > 1u) bad = 1;
    if ((i & 1) && v) odd = 1;
  }
  if (bad) atomicOr(&flagBad, 1);
  if (odd) atomicOr(&flagOdd, 1);
  __syncthreads();
  int mode = flagBad ? 0 : (flagOdd ? 1 : 2);  // 0=bool8, 1=int32, 2=int64
  for (int b = tid; b < B_; b += 256) {
    int cnt = 0;
    if (mode == 0) {
      const unsigned char* mb = (const unsigned char*)maskw;
      for (int t = 0; t < T_; ++t) cnt += (mb[b * T_ + t] != 0);
    } else if (mode == 1) {
      for (int t = 0; t < T_; ++t) cnt += (maskw[b * T_ + t] != 0);
    } else {
      for (int t = 0; t < T_; ++t) cnt += (maskw[(size_t)(b * T_ + t) * 2] != 0);
    }
    if (cnt < 1) cnt = 1;
    lengths[b] = cnt;
  }
}

// ---------------- pack wih: wpkA[d][us][k4(32)][g(64)][4] ----------------
__global__ void k_packw3A(const float* __restrict__ wih_f, const float* __restrict__ wih_b,
                          float* __restrict__ wpkA) {
  int e = blockIdx.x * 256 + threadIdx.x;
  if (e >= 262144) return;
  int p  = e & 3;
  int g  = (e >> 2) & 63;
  int k4 = (e >> 8) & 31;
  int us = (e >> 13) & 15;
  int d  = (e >> 17) & 1;
  int brow = (g >> 4) * 256 + us * 16 + (g & 15);
  const float* wih = d ? wih_b : wih_f;
  wpkA[e] = wih[brow * E_ + k4 * 4 + p];
}

// ---------------- pack whh: wpkB[d][us][k4(64)][g(64)][4] ----------------
__global__ void k_packw3B(const float* __restrict__ whh_f, const float* __restrict__ whh_b,
                          float* __restrict__ wpkB) {
  int e = blockIdx.x * 256 + threadIdx.x;
  if (e >= 524288) return;
  int p  = e & 3;
  int g  = (e >> 2) & 63;
  int k4 = (e >> 8) & 63;
  int us = (e >> 14) & 15;
  int d  = (e >> 18) & 1;
  int brow = (g >> 4) * 256 + us * 16 + (g & 15);
  const float* whh = d ? whh_b : whh_f;
  wpkB[e] = whh[brow * H_ + k4 * 4 + p];
}

__global__ void k_bias(const float* __restrict__ bih_f, const float* __restrict__ bhh_f,
                       const float* __restrict__ bih_b, const float* __restrict__ bhh_b,
                       float* __restrict__ bias) {
  int e = blockIdx.x * 256 + threadIdx.x;
  if (e >= 2 * G4H) return;
  int d = e >> 10, j = e & 1023;
  bias[e] = d ? (bih_b[j] + bhh_b[j]) : (bih_f[j] + bhh_f[j]);
}

// ---------------- embedding gather ----------------
__global__ void k_gather(const int* __restrict__ tokens, const float* __restrict__ embed,
                         float* __restrict__ x) {
  int idx = blockIdx.x * 256 + threadIdx.x;
  int p = idx >> 5, e4 = idx & 31;
  int tok = tokens[p];
  ((float4*)x)[(size_t)p * 32 + e4] = ((const float4*)embed)[(size_t)tok * 32 + e4];
}

// ---------------- zero sync flags ----------------
__global__ void k_zero(int* __restrict__ flags) {
  int i = blockIdx.x * 256 + threadIdx.x;
  if (i < 16384) flags[i] = 0;
}

// ---------------- fused LSTM v5: x-GEMM hoisted above the flag wait ----------------
// 256 WGs = 2 dirs x 8 rowgroups(16 rows) x 16 unit-slices. 512 thr = 2 k-halves x
// (32 gate-pairs x 8 row-pairs), per-thread 2x2 tile. Phase X (x-part, h-independent)
// runs BEFORE the flag wait; hout HBM write deferred past the release.
__global__ __launch_bounds__(512) void k_lstm5(const float* __restrict__ x,
    const float* __restrict__ wpkA, const float* __restrict__ wpkB,
    const float* __restrict__ bias,
    float* __restrict__ hf, float* __restrict__ hb,
    float* __restrict__ hx, int* __restrict__ flags) {
  const int wg = blockIdx.x;
  const int us = wg & 15;
  const int rb = (wg >> 4) & 7;
  const int d  = wg >> 7;
  const int b0 = rb * 16;
  const int tid = threadIdx.x;
  __shared__ float4 wA[32 * 64];      // 32 KB  x-weights slice
  __shared__ float4 wB[64 * 64];      // 64 KB  h-weights slice
  __shared__ float4 vx[32 * 16];      // 8 KB   x_t tile
  __shared__ float4 vLh[64 * 16];     // 16 KB  h_{t-1} tile
  __shared__ float  gbuf2[2 * 64 * 17];  // 8.7 KB partial-reduce

  // stage weights once
  {
    const float4* srcA = (const float4*)(wpkA + (size_t)(d * 16 + us) * 8192);
    for (int i = tid; i < 2048; i += 512) wA[i] = srcA[i];
    const float4* srcB = (const float4*)(wpkB + (size_t)(d * 16 + us) * 16384);
    for (int i = tid; i < 4096; i += 512) wB[i] = srcB[i];
  }
  // roles
  const int r2 = tid & 7;             // row pair
  const int gg = (tid >> 3) & 31;     // gate pair
  const int kc = tid >> 8;            // k half
  const int g0 = 2 * gg, g1 = g0 + 1;
  const int uu = tid & 15, rr = (tid >> 4) & 15;   // cell role (tid<256)
  const int sk4 = tid >> 4, sr = tid & 15;         // x-stage role
  float b_i = 0.f, b_f = 0.f, b_g = 0.f, b_o = 0.f;
  if (tid < 256) {
    b_i = bias[d * G4H + 0 * 256 + us * 16 + uu];
    b_f = bias[d * G4H + 1 * 256 + us * 16 + uu];
    b_g = bias[d * G4H + 2 * 256 + us * 16 + uu];
    b_o = bias[d * G4H + 3 * 256 + us * 16 + uu];
  }
  float creg = 0.f, hn = 0.f;
  float4 xr;
  {
    int t0 = d ? (T_ - 1) : 0;
    xr = *(const float4*)(x + ((size_t)(b0 + sr) * T_ + t0) * E_ + sk4 * 4);
  }
  vx[sk4 * 16 + sr] = xr;             // x(t_0) staged
  {
    int t1 = d ? (T_ - 2) : 1;
    xr = *(const float4*)(x + ((size_t)(b0 + sr) * T_ + t1) * E_ + sk4 * 4);
  }
  float* __restrict__ hout = d ? hb : hf;
  float* __restrict__ hxg = hx + (size_t)(d * 8 + rb) * 8192;  // [par][256u][16r]
  int* __restrict__ flagg = flags + (d * 8 + rb) * 1024;       // 16 flags stride 64
  __syncthreads();   // weights + vx(t_0) staged

  for (int s = 0; s < T_; ++s) {
    const int t = d ? (T_ - 1 - s) : s;
    // ---- phase X: x-partial GEMM (h-independent, hides producer latency) ----
    float a00 = 0.f, a01 = 0.f, a10 = 0.f, a11 = 0.f;
    {
      const float4* wp = wA + kc * 1024;   // 16 k4 per half
      const float4* vp = vx + kc * 256;
#pragma unroll 4
      for (int k4 = 0; k4 < 16; ++k4) {
        float4 w0 = wp[k4 * 64 + g0];
        float4 w1 = wp[k4 * 64 + g1];
        float4 v0 = vp[k4 * 16 + 2 * r2];
        float4 v1 = vp[k4 * 16 + 2 * r2 + 1];
        a00 += w0.x * v0.x + w0.y * v0.y + w0.z * v0.z + w0.w * v0.w;
        a01 += w0.x * v1.x + w0.y * v1.y + w0.z * v1.z + w0.w * v1.w;
        a10 += w1.x * v0.x + w1.y * v0.y + w1.z * v0.z + w1.w * v0.w;
        a11 += w1.x * v1.x + w1.y * v1.y + w1.z * v1.z + w1.w * v1.w;
      }
    }
    // ---- wait for h(s-1) ----
    if (s > 0 && tid < 16) {
      int* fp = flagg + tid * 64;
      while (__hip_atomic_load(fp, __ATOMIC_RELAXED, __HIP_MEMORY_SCOPE_AGENT) < s) {}
    }
    __syncthreads();   // h ready in hx; vLh free
    // ---- stage h ----
    if (s == 0) {
#pragma unroll
      for (int it = 0; it < 8; ++it) {
        int i = it * 512 + tid;
        ((float*)vLh)[(i >> 6) * 64 + (i & 15) * 4 + ((i >> 4) & 3)] = 0.f;
      }
    } else {
      const float* hsrc = hxg + (size_t)(s & 1) * 4096;
#pragma unroll
      for (int it = 0; it < 8; ++it) {
        int i = it * 512 + tid;
        float hv = __hip_atomic_load(hsrc + i, __ATOMIC_RELAXED, __HIP_MEMORY_SCOPE_AGENT);
        ((float*)vLh)[(i >> 6) * 64 + (i & 15) * 4 + ((i >> 4) & 3)] = hv;
      }
    }
    __syncthreads();   // vLh complete
    // ---- phase H: h-partial GEMM (32 k4 per half) ----
    {
      const float4* wp = wB + kc * 2048;
      const float4* vp = vLh + kc * 512;
#pragma unroll 4
      for (int k4 = 0; k4 < 32; ++k4) {
        float4 w0 = wp[k4 * 64 + g0];
        float4 w1 = wp[k4 * 64 + g1];
        float4 v0 = vp[k4 * 16 + 2 * r2];
        float4 v1 = vp[k4 * 16 + 2 * r2 + 1];
        a00 += w0.x * v0.x + w0.y * v0.y + w0.z * v0.z + w0.w * v0.w;
        a01 += w0.x * v1.x + w0.y * v1.y + w0.z * v1.z + w0.w * v1.w;
        a10 += w1.x * v0.x + w1.y * v0.y + w1.z * v0.z + w1.w * v0.w;
        a11 += w1.x * v1.x + w1.y * v1.y + w1.z * v1.z + w1.w * v1.w;
      }
    }
    gbuf2[kc * 1088 + g0 * 17 + 2 * r2]     = a00;
    gbuf2[kc * 1088 + g0 * 17 + 2 * r2 + 1] = a01;
    gbuf2[kc * 1088 + g1 * 17 + 2 * r2]     = a10;
    gbuf2[kc * 1088 + g1 * 17 + 2 * r2 + 1] = a11;
    __syncthreads();   // partials ready
    // ---- cell update ----
    if (tid < 256) {
      float ig = gbuf2[uu * 17 + rr]        + gbuf2[1088 + uu * 17 + rr]        + b_i;
      float fg = gbuf2[(16 + uu) * 17 + rr] + gbuf2[1088 + (16 + uu) * 17 + rr] + b_f;
      float gv = gbuf2[(32 + uu) * 17 + rr] + gbuf2[1088 + (32 + uu) * 17 + rr] + b_g;
      float og = gbuf2[(48 + uu) * 17 + rr] + gbuf2[1088 + (48 + uu) * 17 + rr] + b_o;
      creg = sigf(fg) * creg + sigf(ig) * tanhf(gv);
      hn = sigf(og) * tanhf(creg);
      __hip_atomic_store(hxg + (size_t)((s + 1) & 1) * 4096 + (us * 16 + uu) * 16 + rr, hn,
                         __ATOMIC_RELAXED, __HIP_MEMORY_SCOPE_AGENT);
    }
    asm volatile("s_waitcnt vmcnt(0)" ::: "memory");
    __syncthreads();
    if (tid == 0)
      __hip_atomic_store(flagg + us * 64, s + 1, __ATOMIC_RELEASE, __HIP_MEMORY_SCOPE_AGENT);
    // ---- off-critical-path tail ----
    if (tid < 256)
      hout[((size_t)(b0 + rr) * T_ + t) * H_ + us * 16 + uu] = hn;
    if (s + 1 < T_) {
      vx[sk4 * 16 + sr] = xr;          // x(t_{s+1}) into LDS (read next iter after top barrier)
      if (s + 2 < T_) {
        int tn = d ? (T_ - 3 - s) : (s + 2);
        xr = *(const float4*)(x + ((size_t)(b0 + sr) * T_ + tn) * E_ + sk4 * 4);
      }
    }
    __syncthreads();   // vx(t_{s+1}) visible before next phase X
  }
}

// ---------------- emissions: em = concat(hf,hb) @ w_lin^T + b_lin ----------------
__global__ __launch_bounds__(256) void k_emis(const float* __restrict__ hf, const float* __restrict__ hb,
    const float* __restrict__ w_lin, const float* __restrict__ b_lin, float* __restrict__ em) {
  __shared__ float hsl[8][512];
  __shared__ float red[8][8][K_];
  const int tid = threadIdx.x;
  const int pos0 = blockIdx.x * 8;
  for (int it = 0; it < 4; ++it) {
    int idx = it * 256 + tid;
    int rr = idx >> 7, c4 = idx & 127;
    const float* src = (c4 < 64) ? (hf + ((size_t)(pos0 + rr)) * H_ + (c4 * 4))
                                 : (hb + ((size_t)(pos0 + rr)) * H_ + ((c4 - 64) * 4));
    float4 v = *(const float4*)src;
    *(float4*)&hsl[rr][c4 * 4] = v;
  }
  __syncthreads();
  const int k = tid & 31, jc = tid >> 5;
  float wreg[64];
#pragma unroll
  for (int i4 = 0; i4 < 16; ++i4) {
    float4 w = *(const float4*)(w_lin + (size_t)k * 512 + jc * 64 + i4 * 4);
    wreg[i4 * 4 + 0] = w.x; wreg[i4 * 4 + 1] = w.y; wreg[i4 * 4 + 2] = w.z; wreg[i4 * 4 + 3] = w.w;
  }
  float acc[8];
  for (int rr = 0; rr < 8; ++rr) {
    float a = 0.f;
#pragma unroll
    for (int i4 = 0; i4 < 16; ++i4) {
      float4 h = *(const float4*)&hsl[rr][jc * 64 + i4 * 4];
      a += wreg[i4 * 4 + 0] * h.x + wreg[i4 * 4 + 1] * h.y + wreg[i4 * 4 + 2] * h.z + wreg[i4 * 4 + 3] * h.w;
    }
    acc[rr] = a;
  }
  for (int rr2 = 0; rr2 < 8; ++rr2) red[rr2][jc][k] = acc[rr2];
  __syncthreads();
  {
    int rr = tid >> 5, kk = tid & 31;
    float s = b_lin[kk];
#pragma unroll
    for (int j = 0; j < 8; ++j) s += red[rr][j][kk];
    em[((size_t)(pos0 + rr)) * K_ + kk] = s;
  }
}

// ---------------- Viterbi ----------------
__global__ __launch_bounds__(64) void k_viterbi(const float* __restrict__ em,
    const int* __restrict__ lengths, const float* __restrict__ start_t,
    const float* __restrict__ end_t, const float* __restrict__ trans,
    int* __restrict__ out) {
  const int b = blockIdx.x;
  const int lane = threadIdx.x;
  __shared__ unsigned char hist[T_ - 1][K_];
  __shared__ float sl[K_];
  const int len = lengths[b];
  float tc[K_];
  float score = 0.f;
  if (lane < K_) {
#pragma unroll
    for (int i = 0; i < K_; ++i) tc[i] = trans[i * K_ + lane];
    score = start_t[lane] + em[((size_t)b * T_) * K_ + lane];
  }
  for (int t = 1; t < T_; ++t) {
    float emk = 0.f;
    if (lane < K_) {
      emk = em[((size_t)b * T_ + t) * K_ + lane];
      sl[lane] = score;
    }
    __syncthreads();
    if (lane < K_) {
      float best = sl[0] + tc[0]; int bi = 0;
#pragma unroll
      for (int i = 1; i < K_; ++i) {
        float c = sl[i] + tc[i];
        if (c > best) { best = c; bi = i; }
      }
      hist[t - 1][lane] = (unsigned char)bi;
      if (t < len) score = best + emk;
    }
    __syncthreads();
  }
  if (lane < K_) sl[lane] = score + end_t[lane];
  __syncthreads();
  int* outb = out + (size_t)b * T_;
  for (int t = lane; t < T_; t += 64)
    if (t >= len) outb[t] = 0;
  if (lane == 0) {
    float best = sl[0]; int cur = 0;
    for (int k2 = 1; k2 < K_; ++k2)
      if (sl[k2] > best) { best = sl[k2]; cur = k2; }
    outb[len - 1] = cur;
    for (int t = len - 2; t >= 0; --t) { cur = hist[t][cur]; outb[t] = cur; }
  }
}

extern "C" void kernel_launch(void* const* d_in, const int* in_sizes, int n_in,
                              void* d_out, int out_size, void* d_ws, size_t ws_size,
                              hipStream_t stream) {
  const int* tokens   = (const int*)d_in[0];
  const unsigned* maskw = (const unsigned*)d_in[1];
  const float* embed  = (const float*)d_in[2];
  const float* wih_f  = (const float*)d_in[3];
  const float* whh_f  = (const float*)d_in[4];
  const float* bih_f  = (const float*)d_in[5];
  const float* bhh_f  = (const float*)d_in[6];
  const float* wih_b  = (const float*)d_in[7];
  const float* whh_b  = (const float*)d_in[8];
  const float* bih_b  = (const float*)d_in[9];
  const float* bhh_b  = (const float*)d_in[10];
  const float* w_lin  = (const float*)d_in[11];
  const float* b_lin  = (const float*)d_in[12];
  const float* start_t = (const float*)d_in[13];
  const float* end_t  = (const float*)d_in[14];
  const float* trans  = (const float*)d_in[15];
  int* out = (int*)d_out;
  (void)in_sizes; (void)n_in; (void)out_size; (void)ws_size;

  char* ws = (char*)d_ws;
  size_t off = 0;
  auto alloc = [&](size_t bytes) { size_t o = off; off = (off + bytes + 255) & ~(size_t)255; return o; };
  int*   lengths = (int*)(ws + alloc((size_t)B_ * 4));
  float* wpkA    = (float*)(ws + alloc((size_t)262144 * 4));
  float* wpkB    = (float*)(ws + alloc((size_t)524288 * 4));
  float* bias    = (float*)(ws + alloc((size_t)2 * G4H * 4));
  float* x       = (float*)(ws + alloc((size_t)B_ * T_ * E_ * 4));
  float* hf      = (float*)(ws + alloc((size_t)B_ * T_ * H_ * 4));
  float* hb      = (float*)(ws + alloc((size_t)B_ * T_ * H_ * 4));
  float* em      = (float*)(ws + alloc((size_t)B_ * T_ * K_ * 4));
  float* hx      = (float*)(ws + alloc((size_t)16 * 8192 * 4));
  int*   flags   = (int*)(ws + alloc((size_t)16384 * 4));

  k_lengths<<<dim3(1), dim3(256), 0, stream>>>(maskw, lengths);
  k_packw3A<<<dim3(1024), dim3(256), 0, stream>>>(wih_f, wih_b, wpkA);
  k_packw3B<<<dim3(2048), dim3(256), 0, stream>>>(whh_f, whh_b, wpkB);
  k_bias<<<dim3(8), dim3(256), 0, stream>>>(bih_f, bhh_f, bih_b, bhh_b, bias);
  k_gather<<<dim3((B_ * T_ * E_ / 4) / 256), dim3(256), 0, stream>>>(tokens, embed, x);
  k_zero<<<dim3(64), dim3(256), 0, stream>>>(flags);
  k_lstm5<<<dim3(256), dim3(512), 0, stream>>>(x, wpkA, wpkB, bias, hf, hb, hx, flags);
  k_emis<<<dim3(B_ * T_ / 8), dim3(256), 0, stream>>>(hf, hb, w_lin, b_lin, em);
  k_viterbi<<<dim3(B_), dim3(64), 0, stream>>>(em, lengths, start_t, end_t, trans, out);
}

// Round 14
// 3020.323 us; speedup vs baseline: 1.9859x; 1.0126x over previous
//
#include <hip/hip_runtime.h>
#include <hip/hip_bf16.h>

#define B_ 128
#define T_ 256
#define E_ 128
#define H_ 256
#define K_ 32
#define G4H 1024   // 4*H

__device__ __forceinline__ float sigf(float z) { return 1.0f / (1.0f + expf(-z)); }
__device__ __forceinline__ float dot4(float4 a, float4 b) {
  return a.x * b.x + a.y * b.y + a.z * b.z + a.w * b.w;
}

// ---------------- mask dtype detect + lengths ----------------
__global__ void k_lengths(const unsigned* __restrict__ maskw, int* __restrict__ lengths) {
  __shared__ int flagBad;
  __shared__ int flagOdd;
  int tid = threadIdx.x;
  if (tid == 0) { flagBad = 0; flagOdd = 0; }
  __syncthreads();
  int bad = 0, odd = 0;
  for (int i = tid; i < (B_ * T_) / 4; i += 256) {
    unsigned v = maskw[i];
    if (v > 1u) bad = 1;
    if ((i & 1) && v) odd = 1;
  }
  if (bad) atomicOr(&flagBad, 1);
  if (odd) atomicOr(&flagOdd, 1);
  __syncthreads();
  int mode = flagBad ? 0 : (flagOdd ? 1 : 2);  // 0=bool8, 1=int32, 2=int64
  for (int b = tid; b < B_; b += 256) {
    int cnt = 0;
    if (mode == 0) {
      const unsigned char* mb = (const unsigned char*)maskw;
      for (int t = 0; t < T_; ++t) cnt += (mb[b * T_ + t] != 0);
    } else if (mode == 1) {
      for (int t = 0; t < T_; ++t) cnt += (maskw[b * T_ + t] != 0);
    } else {
      for (int t = 0; t < T_; ++t) cnt += (maskw[(size_t)(b * T_ + t) * 2] != 0);
    }
    if (cnt < 1) cnt = 1;
    lengths[b] = cnt;
  }
}

// ---------------- pack weights: wpk[d][us][slice(8)][iter(12)][gi(4)][gq(16)][4] ----
// g = gq*4+gi (0..63), ty = g>>4, u = g&15, brow = ty*256 + us*16 + u.
// iter 0..3  -> x k4 = slice*4 + iter   (k = k4*4+p, wih row)
// iter 4..11 -> h k4 = slice*8 + iter-4 (k = k4*4+p, whh row)
__global__ void k_packw6(const float* __restrict__ wih_f, const float* __restrict__ whh_f,
                         const float* __restrict__ wih_b, const float* __restrict__ whh_b,
                         float* __restrict__ wpk) {
  int e = blockIdx.x * 256 + threadIdx.x;
  if (e >= 786432) return;
  int p = e & 3;
  int j = (e >> 2) & 63;          // gi*16 + gq
  int gi = j >> 4, gq = j & 15;
  int g = gq * 4 + gi;
  int iter = (e >> 8) % 12;
  int q = (e >> 8) / 12;          // (d*16+us)*8 + slice
  int slice = q & 7;
  int us = (q >> 3) & 15;
  int d = q >> 7;
  int ty = g >> 4, u = g & 15;
  int brow = ty * 256 + us * 16 + u;
  const float* wih = d ? wih_b : wih_f;
  const float* whh = d ? whh_b : whh_f;
  float v;
  if (iter < 4) {
    int k4 = slice * 4 + iter;
    v = wih[brow * E_ + k4 * 4 + p];
  } else {
    int k4 = slice * 8 + (iter - 4);
    v = whh[brow * H_ + k4 * 4 + p];
  }
  wpk[e] = v;
}

__global__ void k_bias(const float* __restrict__ bih_f, const float* __restrict__ bhh_f,
                       const float* __restrict__ bih_b, const float* __restrict__ bhh_b,
                       float* __restrict__ bias) {
  int e = blockIdx.x * 256 + threadIdx.x;
  if (e >= 2 * G4H) return;
  int d = e >> 10, j = e & 1023;
  bias[e] = d ? (bih_b[j] + bhh_b[j]) : (bih_f[j] + bhh_f[j]);
}

// ---------------- embedding gather ----------------
__global__ void k_gather(const int* __restrict__ tokens, const float* __restrict__ embed,
                         float* __restrict__ x) {
  int idx = blockIdx.x * 256 + threadIdx.x;
  int p = idx >> 5, e4 = idx & 31;
  int tok = tokens[p];
  ((float4*)x)[(size_t)p * 32 + e4] = ((const float4*)embed)[(size_t)tok * 32 + e4];
}

// ---------------- zero sync flags ----------------
__global__ void k_zero(int* __restrict__ flags) {
  int i = blockIdx.x * 256 + threadIdx.x;
  if (i < 16384) flags[i] = 0;
}

// ---------------- fused LSTM v6: 4x4 tiles, 8-way k-split, broadcast layout ----------
// 256 WGs = 2 dirs x 8 rowgroups(16 rows) x 16 unit-slices (16 units = 64 gate rows).
// 512 thr = 8 k-slices x 16 gate-quads x 4 row-quads; per k4: 8 ds_read_b128 : 64 FMA.
// w layout [iter][gi][gq] -> 2-way bank alias (free); v reads 16-way broadcast.
// Phase X (x k4s) hoisted above flag wait. Exchange skeleton = R11 (proven).
__global__ __launch_bounds__(512) void k_lstm6(const float* __restrict__ x,
    const float* __restrict__ wpk, const float* __restrict__ bias,
    float* __restrict__ hf, float* __restrict__ hb,
    float* __restrict__ hx, int* __restrict__ flags) {
  const int wg = blockIdx.x;
  const int us = wg & 15;
  const int rb = (wg >> 4) & 7;
  const int d  = wg >> 7;
  const int b0 = rb * 16;
  const int tid = threadIdx.x;
  __shared__ float4 wL[8 * 12 * 64];   // 96 KB [slice][iter][gi][gq]
  __shared__ float4 vx[32 * 16];       // 8 KB  [k4][r]
  __shared__ float4 vLh[64 * 16];      // 16 KB [k4][r]
  __shared__ float  gbuf[8 * 64 * 17]; // 34 KB [slice][g][17pad]

  // stage weights once (12 float4 per thread)
  {
    const float4* wsrc = (const float4*)(wpk + (size_t)(d * 16 + us) * 24576);
    for (int i = tid; i < 6144; i += 512) wL[i] = wsrc[i];
  }
  // roles
  const int slice = tid >> 6;          // 0..7 (wave-uniform)
  const int gq = (tid >> 2) & 15;      // gate quad
  const int rq = tid & 3;              // row quad
  const int uu = tid & 15, rr = (tid >> 4) & 15;   // cell role (tid<256)
  const int sk4 = tid >> 4, sr = tid & 15;         // x-stage role
  float b_i = 0.f, b_f = 0.f, b_g = 0.f, b_o = 0.f;
  if (tid < 256) {
    b_i = bias[d * G4H + 0 * 256 + us * 16 + uu];
    b_f = bias[d * G4H + 1 * 256 + us * 16 + uu];
    b_g = bias[d * G4H + 2 * 256 + us * 16 + uu];
    b_o = bias[d * G4H + 3 * 256 + us * 16 + uu];
  }
  float creg = 0.f, hn = 0.f;
  float4 xr;
  {
    int t0 = d ? (T_ - 1) : 0;
    xr = *(const float4*)(x + ((size_t)(b0 + sr) * T_ + t0) * E_ + sk4 * 4);
  }
  vx[sk4 * 16 + sr] = xr;             // x(t_0) staged
  {
    int t1 = d ? (T_ - 2) : 1;
    xr = *(const float4*)(x + ((size_t)(b0 + sr) * T_ + t1) * E_ + sk4 * 4);
  }
  float* __restrict__ hout = d ? hb : hf;
  float* __restrict__ hxg = hx + (size_t)(d * 8 + rb) * 8192;  // [par][256u][16r]
  int* __restrict__ flagg = flags + (d * 8 + rb) * 1024;       // 16 flags stride 64
  const float4* wbase = wL + slice * 12 * 64;
  __syncthreads();   // weights + vx(t_0) staged

  for (int s = 0; s < T_; ++s) {
    const int t = d ? (T_ - 1 - s) : s;
    // ---- phase X: x-partial GEMM (4 k4s per slice, h-independent) ----
    float a00 = 0.f, a01 = 0.f, a02 = 0.f, a03 = 0.f;
    float a10 = 0.f, a11 = 0.f, a12 = 0.f, a13 = 0.f;
    float a20 = 0.f, a21 = 0.f, a22 = 0.f, a23 = 0.f;
    float a30 = 0.f, a31 = 0.f, a32 = 0.f, a33 = 0.f;
#pragma unroll
    for (int it = 0; it < 4; ++it) {
      const float4* wp = wbase + it * 64;
      const float4* vp = vx + (slice * 4 + it) * 16 + rq * 4;
      float4 w0 = wp[gq], w1 = wp[16 + gq], w2 = wp[32 + gq], w3 = wp[48 + gq];
      float4 v0 = vp[0], v1 = vp[1], v2 = vp[2], v3 = vp[3];
      a00 += dot4(w0, v0); a01 += dot4(w0, v1); a02 += dot4(w0, v2); a03 += dot4(w0, v3);
      a10 += dot4(w1, v0); a11 += dot4(w1, v1); a12 += dot4(w1, v2); a13 += dot4(w1, v3);
      a20 += dot4(w2, v0); a21 += dot4(w2, v1); a22 += dot4(w2, v2); a23 += dot4(w2, v3);
      a30 += dot4(w3, v0); a31 += dot4(w3, v1); a32 += dot4(w3, v2); a33 += dot4(w3, v3);
    }
    // ---- wait for h(s-1) ----
    if (s > 0 && tid < 16) {
      int* fp = flagg + tid * 64;
      while (__hip_atomic_load(fp, __ATOMIC_RELAXED, __HIP_MEMORY_SCOPE_AGENT) < s) {}
    }
    __syncthreads();   // h ready in hx; vLh free
    // ---- stage h ----
    if (s == 0) {
#pragma unroll
      for (int it = 0; it < 8; ++it) {
        int i = it * 512 + tid;
        ((float*)vLh)[(i >> 6) * 64 + (i & 15) * 4 + ((i >> 4) & 3)] = 0.f;
      }
    } else {
      const float* hsrc = hxg + (size_t)(s & 1) * 4096;
#pragma unroll
      for (int it = 0; it < 8; ++it) {
        int i = it * 512 + tid;
        float hv = __hip_atomic_load(hsrc + i, __ATOMIC_RELAXED, __HIP_MEMORY_SCOPE_AGENT);
        ((float*)vLh)[(i >> 6) * 64 + (i & 15) * 4 + ((i >> 4) & 3)] = hv;
      }
    }
    __syncthreads();   // vLh complete
    // ---- phase H: h-partial GEMM (8 k4s per slice) ----
#pragma unroll
    for (int it = 0; it < 8; ++it) {
      const float4* wp = wbase + (4 + it) * 64;
      const float4* vp = vLh + (slice * 8 + it) * 16 + rq * 4;
      float4 w0 = wp[gq], w1 = wp[16 + gq], w2 = wp[32 + gq], w3 = wp[48 + gq];
      float4 v0 = vp[0], v1 = vp[1], v2 = vp[2], v3 = vp[3];
      a00 += dot4(w0, v0); a01 += dot4(w0, v1); a02 += dot4(w0, v2); a03 += dot4(w0, v3);
      a10 += dot4(w1, v0); a11 += dot4(w1, v1); a12 += dot4(w1, v2); a13 += dot4(w1, v3);
      a20 += dot4(w2, v0); a21 += dot4(w2, v1); a22 += dot4(w2, v2); a23 += dot4(w2, v3);
      a30 += dot4(w3, v0); a31 += dot4(w3, v1); a32 += dot4(w3, v2); a33 += dot4(w3, v3);
    }
    // write partials: gate g = gq*4+gi, rows rq*4+ri
    {
      float* gb = gbuf + slice * 1088 + (gq * 4) * 17 + rq * 4;
      gb[0] = a00; gb[1] = a01; gb[2] = a02; gb[3] = a03;
      gb[17 + 0] = a10; gb[17 + 1] = a11; gb[17 + 2] = a12; gb[17 + 3] = a13;
      gb[34 + 0] = a20; gb[34 + 1] = a21; gb[34 + 2] = a22; gb[34 + 3] = a23;
      gb[51 + 0] = a30; gb[51 + 1] = a31; gb[51 + 2] = a32; gb[51 + 3] = a33;
    }
    __syncthreads();   // partials ready
    // ---- cell update: tid<256 -> (unit uu, row rr) ----
    if (tid < 256) {
      float ig = 0.f, fg = 0.f, gv = 0.f, og = 0.f;
#pragma unroll
      for (int sl = 0; sl < 8; ++sl) {
        const float* gb = gbuf + sl * 1088;
        ig += gb[(0 * 16 + uu) * 17 + rr];
        fg += gb[(1 * 16 + uu) * 17 + rr];
        gv += gb[(2 * 16 + uu) * 17 + rr];
        og += gb[(3 * 16 + uu) * 17 + rr];
      }
      ig += b_i; fg += b_f; gv += b_g; og += b_o;
      creg = sigf(fg) * creg + sigf(ig) * tanhf(gv);
      hn = sigf(og) * tanhf(creg);
      __hip_atomic_store(hxg + (size_t)((s + 1) & 1) * 4096 + (us * 16 + uu) * 16 + rr, hn,
                         __ATOMIC_RELAXED, __HIP_MEMORY_SCOPE_AGENT);
    }
    asm volatile("s_waitcnt vmcnt(0)" ::: "memory");
    __syncthreads();
    if (tid == 0)
      __hip_atomic_store(flagg + us * 64, s + 1, __ATOMIC_RELEASE, __HIP_MEMORY_SCOPE_AGENT);
    // ---- off-critical-path tail ----
    if (tid < 256)
      hout[((size_t)(b0 + rr) * T_ + t) * H_ + us * 16 + uu] = hn;
    if (s + 1 < T_) {
      vx[sk4 * 16 + sr] = xr;          // x(t_{s+1}) into LDS
      if (s + 2 < T_) {
        int tn = d ? (T_ - 3 - s) : (s + 2);
        xr = *(const float4*)(x + ((size_t)(b0 + sr) * T_ + tn) * E_ + sk4 * 4);
      }
    }
    __syncthreads();   // vx(t_{s+1}) visible before next phase X
  }
}

// ---------------- emissions: em = concat(hf,hb) @ w_lin^T + b_lin ----------------
__global__ __launch_bounds__(256) void k_emis(const float* __restrict__ hf, const float* __restrict__ hb,
    const float* __restrict__ w_lin, const float* __restrict__ b_lin, float* __restrict__ em) {
  __shared__ float hsl[8][512];
  __shared__ float red[8][8][K_];
  const int tid = threadIdx.x;
  const int pos0 = blockIdx.x * 8;
  for (int it = 0; it < 4; ++it) {
    int idx = it * 256 + tid;
    int rr = idx >> 7, c4 = idx & 127;
    const float* src = (c4 < 64) ? (hf + ((size_t)(pos0 + rr)) * H_ + (c4 * 4))
                                 : (hb + ((size_t)(pos0 + rr)) * H_ + ((c4 - 64) * 4));
    float4 v = *(const float4*)src;
    *(float4*)&hsl[rr][c4 * 4] = v;
  }
  __syncthreads();
  const int k = tid & 31, jc = tid >> 5;
  float wreg[64];
#pragma unroll
  for (int i4 = 0; i4 < 16; ++i4) {
    float4 w = *(const float4*)(w_lin + (size_t)k * 512 + jc * 64 + i4 * 4);
    wreg[i4 * 4 + 0] = w.x; wreg[i4 * 4 + 1] = w.y; wreg[i4 * 4 + 2] = w.z; wreg[i4 * 4 + 3] = w.w;
  }
  float acc[8];
  for (int rr = 0; rr < 8; ++rr) {
    float a = 0.f;
#pragma unroll
    for (int i4 = 0; i4 < 16; ++i4) {
      float4 h = *(const float4*)&hsl[rr][jc * 64 + i4 * 4];
      a += wreg[i4 * 4 + 0] * h.x + wreg[i4 * 4 + 1] * h.y + wreg[i4 * 4 + 2] * h.z + wreg[i4 * 4 + 3] * h.w;
    }
    acc[rr] = a;
  }
  for (int rr2 = 0; rr2 < 8; ++rr2) red[rr2][jc][k] = acc[rr2];
  __syncthreads();
  {
    int rr = tid >> 5, kk = tid & 31;
    float s = b_lin[kk];
#pragma unroll
    for (int j = 0; j < 8; ++j) s += red[rr][j][kk];
    em[((size_t)(pos0 + rr)) * K_ + kk] = s;
  }
}

// ---------------- Viterbi ----------------
__global__ __launch_bounds__(64) void k_viterbi(const float* __restrict__ em,
    const int* __restrict__ lengths, const float* __restrict__ start_t,
    const float* __restrict__ end_t, const float* __restrict__ trans,
    int* __restrict__ out) {
  const int b = blockIdx.x;
  const int lane = threadIdx.x;
  __shared__ unsigned char hist[T_ - 1][K_];
  __shared__ float sl[K_];
  const int len = lengths[b];
  float tc[K_];
  float score = 0.f;
  if (lane < K_) {
#pragma unroll
    for (int i = 0; i < K_; ++i) tc[i] = trans[i * K_ + lane];
    score = start_t[lane] + em[((size_t)b * T_) * K_ + lane];
  }
  for (int t = 1; t < T_; ++t) {
    float emk = 0.f;
    if (lane < K_) {
      emk = em[((size_t)b * T_ + t) * K_ + lane];
      sl[lane] = score;
    }
    __syncthreads();
    if (lane < K_) {
      float best = sl[0] + tc[0]; int bi = 0;
#pragma unroll
      for (int i = 1; i < K_; ++i) {
        float c = sl[i] + tc[i];
        if (c > best) { best = c; bi = i; }
      }
      hist[t - 1][lane] = (unsigned char)bi;
      if (t < len) score = best + emk;
    }
    __syncthreads();
  }
  if (lane < K_) sl[lane] = score + end_t[lane];
  __syncthreads();
  int* outb = out + (size_t)b * T_;
  for (int t = lane; t < T_; t += 64)
    if (t >= len) outb[t] = 0;
  if (lane == 0) {
    float best = sl[0]; int cur = 0;
    for (int k2 = 1; k2 < K_; ++k2)
      if (sl[k2] > best) { best = sl[k2]; cur = k2; }
    outb[len - 1] = cur;
    for (int t = len - 2; t >= 0; --t) { cur = hist[t][cur]; outb[t] = cur; }
  }
}

extern "C" void kernel_launch(void* const* d_in, const int* in_sizes, int n_in,
                              void* d_out, int out_size, void* d_ws, size_t ws_size,
                              hipStream_t stream) {
  const int* tokens   = (const int*)d_in[0];
  const unsigned* maskw = (const unsigned*)d_in[1];
  const float* embed  = (const float*)d_in[2];
  const float* wih_f  = (const float*)d_in[3];
  const float* whh_f  = (const float*)d_in[4];
  const float* bih_f  = (const float*)d_in[5];
  const float* bhh_f  = (const float*)d_in[6];
  const float* wih_b  = (const float*)d_in[7];
  const float* whh_b  = (const float*)d_in[8];
  const float* bih_b  = (const float*)d_in[9];
  const float* bhh_b  = (const float*)d_in[10];
  const float* w_lin  = (const float*)d_in[11];
  const float* b_lin  = (const float*)d_in[12];
  const float* start_t = (const float*)d_in[13];
  const float* end_t  = (const float*)d_in[14];
  const float* trans  = (const float*)d_in[15];
  int* out = (int*)d_out;
  (void)in_sizes; (void)n_in; (void)out_size; (void)ws_size;

  char* ws = (char*)d_ws;
  size_t off = 0;
  auto alloc = [&](size_t bytes) { size_t o = off; off = (off + bytes + 255) & ~(size_t)255; return o; };
  int*   lengths = (int*)(ws + alloc((size_t)B_ * 4));
  float* wpk     = (float*)(ws + alloc((size_t)786432 * 4));
  float* bias    = (float*)(ws + alloc((size_t)2 * G4H * 4));
  float* x       = (float*)(ws + alloc((size_t)B_ * T_ * E_ * 4));
  float* hf      = (float*)(ws + alloc((size_t)B_ * T_ * H_ * 4));
  float* hb      = (float*)(ws + alloc((size_t)B_ * T_ * H_ * 4));
  float* em      = (float*)(ws + alloc((size_t)B_ * T_ * K_ * 4));
  float* hx      = (float*)(ws + alloc((size_t)16 * 8192 * 4));
  int*   flags   = (int*)(ws + alloc((size_t)16384 * 4));

  k_lengths<<<dim3(1), dim3(256), 0, stream>>>(maskw, lengths);
  k_packw6<<<dim3(3072), dim3(256), 0, stream>>>(wih_f, whh_f, wih_b, whh_b, wpk);
  k_bias<<<dim3(8), dim3(256), 0, stream>>>(bih_f, bhh_f, bih_b, bhh_b, bias);
  k_gather<<<dim3((B_ * T_ * E_ / 4) / 256), dim3(256), 0, stream>>>(tokens, embed, x);
  k_zero<<<dim3(64), dim3(256), 0, stream>>>(flags);
  k_lstm6<<<dim3(256), dim3(512), 0, stream>>>(x, wpk, bias, hf, hb, hx, flags);
  k_emis<<<dim3(B_ * T_ / 8), dim3(256), 0, stream>>>(hf, hb, w_lin, b_lin, em);
  k_viterbi<<<dim3(B_), dim3(64), 0, stream>>>(em, lengths, start_t, end_t, trans, out);
}